// Round 2
// baseline (2699.542 us; speedup 1.0000x reference)
//
#include <hip/hip_runtime.h>
#include <hip/hip_bf16.h>
#include <math.h>

// N=100000, D=128, H=8, HID=256, QK=64, V=64, PSI_HID=256, OUT=128
#define NPTS 100000
#define NPAD2 100096          // 391 * 256
#define NGROUPS 391

typedef __bf16 bf16x8 __attribute__((ext_vector_type(8)));
typedef float f32x4 __attribute__((ext_vector_type(4)));

#define MFMA16(a, b, c) __builtin_amdgcn_mfma_f32_16x16x32_bf16((a), (b), (c), 0, 0, 0)

// swizzles (element-index XOR of bits 3..5, i.e. 16B granule within the row)
#define SW1(row) (((row) & 7) << 3)
#define SW2(row) ((((row) ^ ((row) >> 3)) & 7) << 3)

// ---------- prep: coordinates -> bf16, zero-padded ----------
__global__ void k_prep_x(const float* __restrict__ coords, __bf16* __restrict__ Xb) {
  const int total = NPAD2 * 16;  // chunks of 8 elems
  for (int c = blockIdx.x * 256 + threadIdx.x; c < total; c += gridDim.x * 256) {
    int row = c >> 4;
    int e8 = (c & 15) << 3;
    bf16x8 v = {};
    if (row < NPTS) {
      const float4* p = (const float4*)(coords + (size_t)row * 128 + e8);
      float4 f0 = p[0], f1 = p[1];
      v[0] = (__bf16)f0.x; v[1] = (__bf16)f0.y; v[2] = (__bf16)f0.z; v[3] = (__bf16)f0.w;
      v[4] = (__bf16)f1.x; v[5] = (__bf16)f1.y; v[6] = (__bf16)f1.z; v[7] = (__bf16)f1.w;
    }
    *(bf16x8*)(Xb + (size_t)row * 128 + e8) = v;
  }
}

// ---------- prep: weights cast/transpose + zero kv/sumk ----------
__global__ void k_prep_w(const float* __restrict__ Wq0, const float* __restrict__ Wk0,
                         const float* __restrict__ Wv0, const float* __restrict__ Wq1,
                         const float* __restrict__ Wk1, const float* __restrict__ Wv1,
                         const float* __restrict__ Wp0, const float* __restrict__ Wp1,
                         __bf16* __restrict__ W0t, __bf16* __restrict__ W1t,
                         __bf16* __restrict__ Wp0t, __bf16* __restrict__ Wp1t,
                         float* __restrict__ kvz) {
  for (int i = blockIdx.x * 256 + threadIdx.x; i < 1376768; i += gridDim.x * 256) {
    if (i < 786432) {                      // W0t [24][256][128]
      int g = i >> 15, j = i & 32767;
      int mat = g >> 3, h = g & 7, mcol = j >> 7, k = j & 127;
      const float* src = (mat == 0) ? Wq0 : (mat == 1) ? Wk0 : Wv0;
      W0t[i] = (__bf16)src[h * 32768 + k * 256 + mcol];
    } else if (i < 1179648) {              // W1t [24][64][256]
      int t = i - 786432;
      int g = t >> 14, j = t & 16383;
      int mat = g >> 3, h = g & 7, ocol = j >> 8, k = j & 255;
      const float* src = (mat == 0) ? Wq1 : (mat == 1) ? Wk1 : Wv1;
      W1t[t] = (__bf16)src[h * 16384 + k * 64 + ocol];
    } else if (i < 1310720) {              // Wp0t [256][512]
      int t = i - 1179648;
      int col = t >> 9, k = t & 511;
      Wp0t[t] = (__bf16)Wp0[k * 256 + col];
    } else if (i < 1343488) {              // Wp1t [128][256]
      int t = i - 1310720;
      int col = t >> 8, k = t & 255;
      Wp1t[t] = (__bf16)Wp1[k * 128 + col];
    } else {                               // zero kv (32768) + sumk (512)
      kvz[i - 1343488] = 0.f;
    }
  }
}

// ---------- fused QKV MLPs + kv/sumk reduction ----------
// 256 blocks x 512 thr, 1 block/CU. blocks [0,80): q-path; [80,256): kv-path.
__global__ __launch_bounds__(512, 2) void k_mlp(
    const __bf16* __restrict__ Xb, const float* __restrict__ mask,
    const __bf16* __restrict__ W0t, const __bf16* __restrict__ W1t,
    const float* __restrict__ bq0, const float* __restrict__ bq1,
    const float* __restrict__ bk0, const float* __restrict__ bk1,
    const float* __restrict__ bv0, const float* __restrict__ bv1,
    __bf16* __restrict__ qk_ws, float* __restrict__ kv, float* __restrict__ sumk)
{
  __shared__ __bf16 smem[65536];          // 128 KB
  __bf16* sW0 = smem;                     // 32768 elems: [256 col][128 k] swizzled SW1
  __bf16* sHV = smem + 32768;             // 16384: 8 waves x [32][64] (kv: also sV [256][64] SW2)
  __bf16* sKK = smem + 49152;             // 16384: kv: sKK [256][64] SW2; q: sW1q [64][256] SW1

  const int tid = threadIdx.x;
  const int w = tid >> 6, lane = tid & 63, l15 = lane & 15, lg = lane >> 4;
  const int bx = blockIdx.x;
  __bf16* myH = sHV + w * 2048;

  if (bx < 80) {
    // ================= q path =================
    const int h = bx / 10, chunk = bx % 10;
    const __bf16* w0 = W0t + (size_t)h * 32768;
    const __bf16* w1 = W1t + (size_t)h * 16384;
    #pragma unroll
    for (int i = 0; i < 8; ++i) {
      int u = tid + i * 512;
      int col = u >> 4, koff = (u & 15) << 3;
      *(bf16x8*)&sW0[(col * 128 + koff) ^ SW1(col)] = *(const bf16x8*)(w0 + col * 128 + koff);
    }
    #pragma unroll
    for (int i = 0; i < 4; ++i) {
      int u = tid + i * 512;
      int oc = u >> 5, koff = (u & 31) << 3;
      *(bf16x8*)&sKK[(oc * 256 + koff) ^ SW1(oc)] = *(const bf16x8*)(w1 + oc * 256 + koff);
    }
    __syncthreads();
    float b1r[4];
    #pragma unroll
    for (int f = 0; f < 4; ++f) b1r[f] = bq1[h * 64 + f * 16 + l15];

    for (int rg = chunk; rg < NGROUPS; rg += 10) {
      const int base = rg * 256 + w * 32;
      bf16x8 ax[2][4];
      #pragma unroll
      for (int rt = 0; rt < 2; ++rt)
        #pragma unroll
        for (int ks = 0; ks < 4; ++ks)
          ax[rt][ks] = *(const bf16x8*)(Xb + (size_t)(base + rt * 16 + l15) * 128 + ks * 32 + lg * 8);
      float mv[2][4];
      #pragma unroll
      for (int rt = 0; rt < 2; ++rt)
        #pragma unroll
        for (int r = 0; r < 4; ++r) {
          int grow = base + rt * 16 + lg * 4 + r;
          mv[rt][r] = (grow < NPTS) ? mask[grow] : 0.f;
        }
      f32x4 acc2[2][4] = {};
      #pragma unroll
      for (int c = 0; c < 4; ++c) {
        f32x4 a1[2][4] = {};
        #pragma unroll
        for (int ks = 0; ks < 4; ++ks) {
          #pragma unroll
          for (int f = 0; f < 4; ++f) {
            int bc = c * 64 + f * 16 + l15;
            bf16x8 bv = *(const bf16x8*)&sW0[(bc * 128 + ks * 32 + lg * 8) ^ SW1(l15)];
            a1[0][f] = MFMA16(ax[0][ks], bv, a1[0][f]);
            a1[1][f] = MFMA16(ax[1][ks], bv, a1[1][f]);
          }
        }
        #pragma unroll
        for (int f = 0; f < 4; ++f) {
          float bias = bq0[h * 256 + c * 64 + f * 16 + l15];
          #pragma unroll
          for (int rt = 0; rt < 2; ++rt)
            #pragma unroll
            for (int r = 0; r < 4; ++r) {
              int row = rt * 16 + lg * 4 + r;
              float val = a1[rt][f][r] + bias;
              val = val > 0.f ? val : 0.f;
              myH[(row * 64 + f * 16 + l15) ^ SW1(row)] = (__bf16)val;
            }
        }
        #pragma unroll
        for (int ks2 = 0; ks2 < 2; ++ks2) {
          bf16x8 aH[2];
          #pragma unroll
          for (int rt = 0; rt < 2; ++rt)
            aH[rt] = *(const bf16x8*)&myH[((rt * 16 + l15) * 64 + ks2 * 32 + lg * 8) ^ SW1(l15)];
          #pragma unroll
          for (int f = 0; f < 4; ++f) {
            bf16x8 bw = *(const bf16x8*)&sKK[((f * 16 + l15) * 256 + c * 64 + ks2 * 32 + lg * 8) ^ SW1(l15)];
            acc2[0][f] = MFMA16(aH[0], bw, acc2[0][f]);
            acc2[1][f] = MFMA16(aH[1], bw, acc2[1][f]);
          }
        }
      }
      // epilogue: phi(q*m) -> repack via myH -> coalesced store
      #pragma unroll
      for (int f = 0; f < 4; ++f)
        #pragma unroll
        for (int rt = 0; rt < 2; ++rt)
          #pragma unroll
          for (int r = 0; r < 4; ++r) {
            float val = (acc2[rt][f][r] + b1r[f]) * mv[rt][r];
            float pq = val > 0.f ? val + 1.f : __expf(val);
            int row = rt * 16 + lg * 4 + r;
            myH[(row * 64 + f * 16 + l15) ^ SW1(row)] = (__bf16)pq;
          }
      #pragma unroll
      for (int p = 0; p < 4; ++p) {
        int row = p * 8 + (lane >> 3), coff = (lane & 7) << 3;
        bf16x8 v = *(const bf16x8*)&myH[(row * 64 + coff) ^ SW1(row)];
        *(bf16x8*)(qk_ws + ((size_t)h * NPAD2 + base + row) * 64 + coff) = v;
      }
    }
  } else {
    // ================= kv path =================
    const int i2 = bx - 80;
    const int h = i2 / 22, chunk = i2 % 22;
    float b1m[2][4];
    #pragma unroll
    for (int f = 0; f < 4; ++f) {
      b1m[0][f] = bk1[h * 64 + f * 16 + l15];
      b1m[1][f] = bv1[h * 64 + f * 16 + l15];
    }
    f32x4 akv[2] = {};
    float ask = 0.f;
    const int kqt = w >> 1;
    const int jt0 = (w & 1) * 2;

    for (int rg = chunk; rg < NGROUPS; rg += 22) {
      const int base = rg * 256 + w * 32;
      bf16x8 ax[2][4];
      #pragma unroll
      for (int rt = 0; rt < 2; ++rt)
        #pragma unroll
        for (int ks = 0; ks < 4; ++ks)
          ax[rt][ks] = *(const bf16x8*)(Xb + (size_t)(base + rt * 16 + l15) * 128 + ks * 32 + lg * 8);
      float mv[2][4];
      #pragma unroll
      for (int rt = 0; rt < 2; ++rt)
        #pragma unroll
        for (int r = 0; r < 4; ++r) {
          int grow = base + rt * 16 + lg * 4 + r;
          mv[rt][r] = (grow < NPTS) ? mask[grow] : 0.f;
        }

      #pragma unroll
      for (int m = 0; m < 2; ++m) {     // 0 = k, 1 = v
        const __bf16* w0 = W0t + (size_t)((m ? 16 : 8) + h) * 32768;
        const __bf16* w1g = W1t + (size_t)((m ? 16 : 8) + h) * 16384;
        const float* b0 = m ? bv0 : bk0;
        __syncthreads();     // all waves done with previous phase's sW0 / sHV / sKK reads
        #pragma unroll
        for (int i = 0; i < 8; ++i) {
          int u = tid + i * 512;
          int col = u >> 4, koff = (u & 15) << 3;
          *(bf16x8*)&sW0[(col * 128 + koff) ^ SW1(col)] = *(const bf16x8*)(w0 + col * 128 + koff);
        }
        __syncthreads();
        f32x4 acc2[2][4] = {};
        #pragma unroll
        for (int c = 0; c < 4; ++c) {
          f32x4 a1[2][4] = {};
          #pragma unroll
          for (int ks = 0; ks < 4; ++ks) {
            #pragma unroll
            for (int f = 0; f < 4; ++f) {
              int bc = c * 64 + f * 16 + l15;
              bf16x8 bv = *(const bf16x8*)&sW0[(bc * 128 + ks * 32 + lg * 8) ^ SW1(l15)];
              a1[0][f] = MFMA16(ax[0][ks], bv, a1[0][f]);
              a1[1][f] = MFMA16(ax[1][ks], bv, a1[1][f]);
            }
          }
          #pragma unroll
          for (int f = 0; f < 4; ++f) {
            float bias = b0[h * 256 + c * 64 + f * 16 + l15];
            #pragma unroll
            for (int rt = 0; rt < 2; ++rt)
              #pragma unroll
              for (int r = 0; r < 4; ++r) {
                int row = rt * 16 + lg * 4 + r;
                float val = a1[rt][f][r] + bias;
                val = val > 0.f ? val : 0.f;
                myH[(row * 64 + f * 16 + l15) ^ SW1(row)] = (__bf16)val;
              }
          }
          #pragma unroll
          for (int ks2 = 0; ks2 < 2; ++ks2) {
            bf16x8 aH[2];
            #pragma unroll
            for (int rt = 0; rt < 2; ++rt)
              aH[rt] = *(const bf16x8*)&myH[((rt * 16 + l15) * 64 + ks2 * 32 + lg * 8) ^ SW1(l15)];
            #pragma unroll
            for (int f = 0; f < 4; ++f) {
              bf16x8 bw = *(const bf16x8*)(w1g + (size_t)(f * 16 + l15) * 256 + c * 64 + ks2 * 32 + lg * 8);
              acc2[0][f] = MFMA16(aH[0], bw, acc2[0][f]);
              acc2[1][f] = MFMA16(aH[1], bw, acc2[1][f]);
            }
          }
        }
        // epilogue -> sKK (k, phi + pad-zero) or sHV-as-sV (v)
        #pragma unroll
        for (int f = 0; f < 4; ++f)
          #pragma unroll
          for (int rt = 0; rt < 2; ++rt)
            #pragma unroll
            for (int r = 0; r < 4; ++r) {
              float val = (acc2[rt][f][r] + b1m[m][f]) * mv[rt][r];
              int row256 = w * 32 + rt * 16 + lg * 4 + r;
              if (m == 0) {
                int grow = base + rt * 16 + lg * 4 + r;
                float pk = (grow < NPTS) ? (val > 0.f ? val + 1.f : __expf(val)) : 0.f;
                sKK[(row256 * 64 + f * 16 + l15) ^ SW2(row256)] = (__bf16)pk;
              } else {
                sHV[(row256 * 64 + f * 16 + l15) ^ SW2(row256)] = (__bf16)val;
              }
            }
      }
      __syncthreads();     // kk & v tiles complete
      // kv partial: this wave owns (kqt, jt0..jt0+1), K = 256 rows
      #pragma unroll
      for (int ks = 0; ks < 8; ++ks) {
        bf16x8 a;
        #pragma unroll
        for (int e = 0; e < 8; ++e) {
          int n = ks * 32 + lg * 8 + e;
          a[e] = sKK[(n * 64 + kqt * 16 + l15) ^ SW2(n)];
        }
        #pragma unroll
        for (int b = 0; b < 2; ++b) {
          bf16x8 bb;
          #pragma unroll
          for (int e = 0; e < 8; ++e) {
            int n = ks * 32 + lg * 8 + e;
            bb[e] = sHV[(n * 64 + (jt0 + b) * 16 + l15) ^ SW2(n)];
          }
          akv[b] = MFMA16(a, bb, akv[b]);
        }
      }
      // sumk partial
      {
        int kq = tid & 63, r0 = (tid >> 6) * 32;
        #pragma unroll
        for (int i = 0; i < 32; ++i) {
          int row = r0 + i;
          ask += (float)sKK[(row * 64 + kq) ^ SW2(row)];
        }
      }
    }
    // one atomic flush per block
    #pragma unroll
    for (int b = 0; b < 2; ++b)
      #pragma unroll
      for (int r = 0; r < 4; ++r)
        atomicAdd(&kv[(size_t)(h * 64 + kqt * 16 + lg * 4 + r) * 64 + (jt0 + b) * 16 + l15], akv[b][r]);
    atomicAdd(&sumk[h * 64 + (tid & 63)], ask);
  }
}

// ---------- kv f32 [8][k][j] -> kvTe bf16 [8][j][k] ----------
__global__ void k_kvt(const float* __restrict__ kv, __bf16* __restrict__ kvTe) {
  int i = blockIdx.x * 256 + threadIdx.x;
  if (i < 32768) {
    int h = i >> 12, j = (i >> 6) & 63, k = i & 63;
    kvTe[i] = (__bf16)kv[h * 4096 + k * 64 + j];
  }
}

// ---------- attention normalize + psi MLP ----------
__global__ __launch_bounds__(512, 2) void k_cd(
    const float* __restrict__ mask, const __bf16* __restrict__ qk_ws,
    const __bf16* __restrict__ kvTe, const float* __restrict__ sumk,
    const __bf16* __restrict__ Wp0t, const __bf16* __restrict__ Wp1t,
    const float* __restrict__ bp0, const float* __restrict__ bp1,
    float* __restrict__ out)
{
  __shared__ __bf16 sWp0c[16384];   // [256 col][64 k] swizzled SW1
  __shared__ __bf16 sCat[8192];     // 8 x [16][64]
  __shared__ __bf16 sH2[32768];     // 8 x [16][256]
  __shared__ float sSumk[512];

  const int tid = threadIdx.x, w = tid >> 6, lane = tid & 63, l15 = lane & 15, lg = lane >> 4;
  const int rbase = blockIdx.x * 128 + w * 16;
  __bf16* myCat = sCat + w * 1024;
  __bf16* myH2 = sH2 + w * 4096;

  sSumk[tid] = sumk[tid];

  f32x4 acc1[16] = {};
  for (int h = 0; h < 8; ++h) {
    __syncthreads();   // prev head's psi reads done (h=0: sSumk ready)
    #pragma unroll
    for (int i = 0; i < 4; ++i) {
      int u = tid + i * 512;
      int col = u >> 3, koff = (u & 7) << 3;
      *(bf16x8*)&sWp0c[(col * 64 + koff) ^ SW1(col)] =
          *(const bf16x8*)(Wp0t + (size_t)col * 512 + h * 64 + koff);
    }
    __syncthreads();
    bf16x8 axq[2];
    #pragma unroll
    for (int ks = 0; ks < 2; ++ks)
      axq[ks] = *(const bf16x8*)(qk_ws + ((size_t)h * NPAD2 + rbase + l15) * 64 + ks * 32 + lg * 8);
    // num = qk @ kv
    f32x4 accn[4] = {};
    #pragma unroll
    for (int ks = 0; ks < 2; ++ks)
      #pragma unroll
      for (int f = 0; f < 4; ++f) {
        bf16x8 bv = *(const bf16x8*)(kvTe + ((size_t)h * 64 + f * 16 + l15) * 64 + ks * 32 + lg * 8);
        accn[f] = MFMA16(axq[ks], bv, accn[f]);
      }
    // den: per-lane partial (row = l15) + xor-reduce over lg
    float p = 0.f;
    #pragma unroll
    for (int ks = 0; ks < 2; ++ks)
      #pragma unroll
      for (int e = 0; e < 8; ++e)
        p += (float)axq[ks][e] * sSumk[h * 64 + ks * 32 + lg * 8 + e];
    p += __shfl_xor(p, 16);
    p += __shfl_xor(p, 32);
    float dinv[4];
    #pragma unroll
    for (int r = 0; r < 4; ++r) {
      float d = __shfl(p, (lane & 48) + ((lane >> 4) << 2) + r);
      d = (d == 0.f) ? 1e-6f : d;
      dinv[r] = 1.f / d;
    }
    // cat chunk
    #pragma unroll
    for (int f = 0; f < 4; ++f)
      #pragma unroll
      for (int r = 0; r < 4; ++r) {
        int row = lg * 4 + r;
        myCat[(row * 64 + f * 16 + l15) ^ SW1(row)] = (__bf16)(accn[f][r] * dinv[r]);
      }
    // psi layer1 partial
    #pragma unroll
    for (int ks2 = 0; ks2 < 2; ++ks2) {
      bf16x8 aC = *(const bf16x8*)&myCat[(l15 * 64 + ks2 * 32 + lg * 8) ^ SW1(l15)];
      #pragma unroll
      for (int f = 0; f < 16; ++f) {
        bf16x8 bw = *(const bf16x8*)&sWp0c[((f * 16 + l15) * 64 + ks2 * 32 + lg * 8) ^ SW1(l15)];
        acc1[f] = MFMA16(aC, bw, acc1[f]);
      }
    }
  }
  // relu -> myH2
  #pragma unroll
  for (int f = 0; f < 16; ++f) {
    float bias = bp0[f * 16 + l15];
    #pragma unroll
    for (int r = 0; r < 4; ++r) {
      int row = lg * 4 + r;
      float val = acc1[f][r] + bias;
      val = val > 0.f ? val : 0.f;
      myH2[(row * 256 + f * 16 + l15) ^ SW1(row)] = (__bf16)val;
    }
  }
  // layer2
  f32x4 acc2[8] = {};
  #pragma unroll
  for (int ks = 0; ks < 8; ++ks) {
    bf16x8 aH = *(const bf16x8*)&myH2[(l15 * 256 + ks * 32 + lg * 8) ^ SW1(l15)];
    #pragma unroll
    for (int f = 0; f < 8; ++f) {
      bf16x8 bw = *(const bf16x8*)(Wp1t + (size_t)(f * 16 + l15) * 256 + ks * 32 + lg * 8);
      acc2[f] = MFMA16(aH, bw, acc2[f]);
    }
  }
  float mvr[4];
  #pragma unroll
  for (int r = 0; r < 4; ++r) {
    int grow = rbase + lg * 4 + r;
    mvr[r] = (grow < NPTS) ? mask[grow] : 0.f;
  }
  #pragma unroll
  for (int f = 0; f < 8; ++f) {
    int col = f * 16 + l15;
    float bias = bp1[col];
    #pragma unroll
    for (int r = 0; r < 4; ++r) {
      int grow = rbase + lg * 4 + r;
      if (grow < NPTS) out[(size_t)grow * 128 + col] = (acc2[f][r] + bias) * mvr[r];
    }
  }
}

extern "C" void kernel_launch(void* const* d_in, const int* in_sizes, int n_in,
                              void* d_out, int out_size, void* d_ws, size_t ws_size,
                              hipStream_t stream) {
  const float* coords = (const float*)d_in[0];
  const float* mask   = (const float*)d_in[1];
  const float* Wq0 = (const float*)d_in[2];
  const float* bq0 = (const float*)d_in[3];
  const float* Wq1 = (const float*)d_in[4];
  const float* bq1 = (const float*)d_in[5];
  const float* Wk0 = (const float*)d_in[6];
  const float* bk0 = (const float*)d_in[7];
  const float* Wk1 = (const float*)d_in[8];
  const float* bk1 = (const float*)d_in[9];
  const float* Wv0 = (const float*)d_in[10];
  const float* bv0 = (const float*)d_in[11];
  const float* Wv1 = (const float*)d_in[12];
  const float* bv1 = (const float*)d_in[13];
  const float* Wp0 = (const float*)d_in[14];
  const float* bp0 = (const float*)d_in[15];
  const float* Wp1 = (const float*)d_in[16];
  const float* bp1 = (const float*)d_in[17];
  float* out = (float*)d_out;

  char* p = (char*)d_ws;
  __bf16* qk_ws = (__bf16*)p; p += (size_t)8 * NPAD2 * 64 * 2;     // 102,498,304
  __bf16* Xb    = (__bf16*)p; p += (size_t)NPAD2 * 128 * 2;        //  25,624,576
  __bf16* W0t   = (__bf16*)p; p += (size_t)24 * 32768 * 2;         //   1,572,864
  __bf16* W1t   = (__bf16*)p; p += (size_t)24 * 16384 * 2;         //     786,432
  __bf16* Wp0t  = (__bf16*)p; p += (size_t)256 * 512 * 2;          //     262,144
  __bf16* Wp1t  = (__bf16*)p; p += (size_t)128 * 256 * 2;          //      65,536
  float*  kv    = (float*)p;  p += (size_t)8 * 64 * 64 * 4;        //     131,072
  float*  sumk  = (float*)p;  p += (size_t)512 * 4;                //       2,048
  __bf16* kvTe  = (__bf16*)p; p += (size_t)8 * 64 * 64 * 2;        //      65,536

  k_prep_x<<<2048, 256, 0, stream>>>(coords, Xb);
  k_prep_w<<<1024, 256, 0, stream>>>(Wq0, Wk0, Wv0, Wq1, Wk1, Wv1, Wp0, Wp1,
                                     W0t, W1t, Wp0t, Wp1t, kv);
  k_mlp<<<256, 512, 0, stream>>>(Xb, mask, W0t, W1t, bq0, bq1, bk0, bk1, bv0, bv1,
                                 qk_ws, kv, sumk);
  k_kvt<<<128, 256, 0, stream>>>(kv, kvTe);
  k_cd<<<782, 512, 0, stream>>>(mask, qk_ws, kvTe, sumk, Wp0t, Wp1t, bp0, bp1, out);
}

// Round 3
// 1967.999 us; speedup vs baseline: 1.3717x; 1.3717x over previous
//
#include <hip/hip_runtime.h>
#include <hip/hip_bf16.h>
#include <math.h>

// N=100000, D=128, H=8, HID=256, QK=64, V=64, PSI_HID=256, OUT=128
#define NPTS 100000
#define NPAD2 100096          // 1564 * 64 = 3128 * 32 = 782 * 128
#define NG64 1564
#define NG32 3128

typedef __bf16 bf16x8 __attribute__((ext_vector_type(8)));
typedef __bf16 bf16x4 __attribute__((ext_vector_type(4)));
typedef float f32x4 __attribute__((ext_vector_type(4)));

#define MFMA16(a, b, c) __builtin_amdgcn_mfma_f32_16x16x32_bf16((a), (b), (c), 0, 0, 0)
#define SW1(row) (((row) & 7) << 3)

// ---------- prep: coordinates -> bf16, zero-padded ----------
__global__ void k_prep_x(const float* __restrict__ coords, __bf16* __restrict__ Xb) {
  const int total = NPAD2 * 16;  // chunks of 8 elems
  for (int c = blockIdx.x * 256 + threadIdx.x; c < total; c += gridDim.x * 256) {
    int row = c >> 4;
    int e8 = (c & 15) << 3;
    bf16x8 v = {};
    if (row < NPTS) {
      const float4* p = (const float4*)(coords + (size_t)row * 128 + e8);
      float4 f0 = p[0], f1 = p[1];
      v[0] = (__bf16)f0.x; v[1] = (__bf16)f0.y; v[2] = (__bf16)f0.z; v[3] = (__bf16)f0.w;
      v[4] = (__bf16)f1.x; v[5] = (__bf16)f1.y; v[6] = (__bf16)f1.z; v[7] = (__bf16)f1.w;
    }
    *(bf16x8*)(Xb + (size_t)row * 128 + e8) = v;
  }
}

// ---------- prep: weights cast/transpose + zero sumk ----------
__global__ void k_prep_w(const float* __restrict__ Wq0, const float* __restrict__ Wk0,
                         const float* __restrict__ Wv0, const float* __restrict__ Wq1,
                         const float* __restrict__ Wk1, const float* __restrict__ Wv1,
                         const float* __restrict__ Wp0, const float* __restrict__ Wp1,
                         __bf16* __restrict__ W0t, __bf16* __restrict__ W1t,
                         __bf16* __restrict__ Wp0t, __bf16* __restrict__ Wp1t,
                         float* __restrict__ sumk) {
  for (int i = blockIdx.x * 256 + threadIdx.x; i < 1344000; i += gridDim.x * 256) {
    if (i < 786432) {                      // W0t [24][256][128]  (m-col major, k contiguous)
      int g = i >> 15, j = i & 32767;
      int mat = g >> 3, h = g & 7, mcol = j >> 7, k = j & 127;
      const float* src = (mat == 0) ? Wq0 : (mat == 1) ? Wk0 : Wv0;
      W0t[i] = (__bf16)src[h * 32768 + k * 256 + mcol];
    } else if (i < 1179648) {              // W1t [24][64][256]   (o major, k contiguous)
      int t = i - 786432;
      int g = t >> 14, j = t & 16383;
      int mat = g >> 3, h = g & 7, ocol = j >> 8, k = j & 255;
      const float* src = (mat == 0) ? Wq1 : (mat == 1) ? Wk1 : Wv1;
      W1t[t] = (__bf16)src[h * 16384 + k * 64 + ocol];
    } else if (i < 1310720) {              // Wp0t [256][512]
      int t = i - 1179648;
      int col = t >> 9, k = t & 511;
      Wp0t[t] = (__bf16)Wp0[k * 256 + col];
    } else if (i < 1343488) {              // Wp1t [128][256]
      int t = i - 1310720;
      int col = t >> 8, k = t & 255;
      Wp1t[t] = (__bf16)Wp1[k * 128 + col];
    } else {                               // zero sumk (512)
      sumk[i - 1343488] = 0.f;
    }
  }
}

// ---------- fused QKV MLPs + kv/sumk reduction ----------
// 256 blocks x 512 thr. blocks [0,80): q (8h x 10); [80,256): k+v fused (8h x 22).
// Weights staged once; main loops are barrier-free (wave-private LDS).
__global__ __launch_bounds__(512, 2) void k_mlp(
    const __bf16* __restrict__ Xb, const float* __restrict__ mask,
    const __bf16* __restrict__ W0t, const __bf16* __restrict__ W1t,
    const float* __restrict__ bq0, const float* __restrict__ bq1,
    const float* __restrict__ bk0, const float* __restrict__ bk1,
    const float* __restrict__ bv0, const float* __restrict__ bv1,
    __bf16* __restrict__ qk_ws, float* __restrict__ kvp, float* __restrict__ sumk)
{
  __shared__ __bf16 smem[73728];   // 144 KB: sW0 64KB + 8 waves x 10KB private
  __bf16* sW0 = smem;              // [256 col][128 k], SW1-swizzled
  const int tid = threadIdx.x, w = tid >> 6, lane = tid & 63;
  const int l15 = lane & 15, lg = lane >> 4;
  const int bx = blockIdx.x;

  if (bx < 80) {
    // ====================== q path: 64 rows/wave/iter ======================
    const int h = bx / 10, cb = bx % 10;
    const __bf16* w0 = W0t + (size_t)h * 32768;
    const __bf16* w1 = W1t + (size_t)h * 16384;
    __bf16* sH = smem + 32768 + w * 5120;   // uses 4096 elems: [64 row][64 hid] SW1

    #pragma unroll
    for (int i = 0; i < 8; ++i) {
      int u = tid + i * 512;
      int col = u >> 4, ko = (u & 15) << 3;
      *(bf16x8*)&sW0[(col * 128 + ko) ^ SW1(col)] = *(const bf16x8*)(w0 + col * 128 + ko);
    }
    __syncthreads();

    for (int g = cb * 8 + w; g < NG64; g += 80) {
      const int rbase = g * 64;
      bf16x8 ax[4][4];
      #pragma unroll
      for (int jt = 0; jt < 4; ++jt)
        #pragma unroll
        for (int ks = 0; ks < 4; ++ks)
          ax[jt][ks] = *(const bf16x8*)(Xb + (size_t)(rbase + jt * 16 + l15) * 128 + ks * 32 + lg * 8);

      f32x4 acc2[4][4] = {};   // [ft(outcol)][jt(xrow)]  (swapped layer2)
      #pragma unroll
      for (int c = 0; c < 4; ++c) {
        f32x4 a1[4][4] = {};   // [fi(hidcol)][jt(xrow)]  (swapped layer1)
        #pragma unroll
        for (int ks = 0; ks < 4; ++ks) {
          bf16x8 wa[4];
          #pragma unroll
          for (int fi = 0; fi < 4; ++fi) {
            int col = c * 64 + fi * 16 + l15;
            wa[fi] = *(const bf16x8*)&sW0[(col * 128 + ks * 32 + lg * 8) ^ SW1(col)];
          }
          #pragma unroll
          for (int fi = 0; fi < 4; ++fi)
            #pragma unroll
            for (int jt = 0; jt < 4; ++jt)
              a1[fi][jt] = MFMA16(wa[fi], ax[jt][ks], a1[fi][jt]);
        }
        // bias+relu -> sH (packed 8B: lane holds 4 contiguous hid cols)
        #pragma unroll
        for (int fi = 0; fi < 4; ++fi) {
          f32x4 b0q = *(const f32x4*)&bq0[h * 256 + c * 64 + fi * 16 + lg * 4];
          #pragma unroll
          for (int jt = 0; jt < 4; ++jt) {
            bf16x4 hv;
            #pragma unroll
            for (int r = 0; r < 4; ++r) {
              float v = a1[fi][jt][r] + b0q[r];
              hv[r] = (__bf16)(v > 0.f ? v : 0.f);
            }
            int row = jt * 16 + l15;
            *(bf16x4*)&sH[(row * 64 + fi * 16 + lg * 4) ^ SW1(row)] = hv;
          }
        }
        // layer2 partial (swapped): A'=W1 rows (global/L2), B'=H rows (LDS)
        #pragma unroll
        for (int ks2 = 0; ks2 < 2; ++ks2) {
          bf16x8 hb[4], wb[4];
          #pragma unroll
          for (int jt = 0; jt < 4; ++jt) {
            int row = jt * 16 + l15;
            hb[jt] = *(const bf16x8*)&sH[(row * 64 + ks2 * 32 + lg * 8) ^ SW1(row)];
          }
          #pragma unroll
          for (int ft = 0; ft < 4; ++ft)
            wb[ft] = *(const bf16x8*)(w1 + (size_t)(ft * 16 + l15) * 256 + c * 64 + ks2 * 32 + lg * 8);
          #pragma unroll
          for (int ft = 0; ft < 4; ++ft)
            #pragma unroll
            for (int jt = 0; jt < 4; ++jt)
              acc2[ft][jt] = MFMA16(wb[ft], hb[jt], acc2[ft][jt]);
        }
      }
      // epilogue: phi((q+b1)*m) -> packed 8B row-major stores
      float mq[4];
      #pragma unroll
      for (int jt = 0; jt < 4; ++jt) {
        int row = rbase + jt * 16 + l15;
        mq[jt] = (row < NPTS) ? mask[row] : 0.f;
      }
      #pragma unroll
      for (int ft = 0; ft < 4; ++ft) {
        f32x4 b1q = *(const f32x4*)&bq1[h * 64 + ft * 16 + lg * 4];
        #pragma unroll
        for (int jt = 0; jt < 4; ++jt) {
          bf16x4 qv;
          #pragma unroll
          for (int r = 0; r < 4; ++r) {
            float v = (acc2[ft][jt][r] + b1q[r]) * mq[jt];
            qv[r] = (__bf16)(v > 0.f ? v + 1.f : __expf(v));
          }
          *(bf16x4*)(qk_ws + ((size_t)h * NPAD2 + rbase + jt * 16 + l15) * 64 + ft * 16 + lg * 4) = qv;
        }
      }
    }
  } else {
    // ====================== k+v path: 32 rows/wave/iter ======================
    const int i2 = bx - 80, h = i2 / 22, cb = i2 % 22;
    const __bf16* w0k = W0t + (size_t)(8 + h) * 32768;
    const __bf16* w0v = W0t + (size_t)(16 + h) * 32768;
    const __bf16* w1k = W1t + (size_t)(8 + h) * 16384;
    const __bf16* w1v = W1t + (size_t)(16 + h) * 16384;
    __bf16* sKK = smem + 32768 + w * 5120;  // [64 kq][40] (x in 0..31), padded stride
    __bf16* sHV = sKK + 2560;               // aliases: sH [32][64] SW1  /  sVT [64][40]

    #pragma unroll
    for (int i = 0; i < 8; ++i) {
      int u = tid + i * 512;
      int col = u >> 4, ko = (u & 15) << 3;
      *(bf16x8*)&sW0[(col * 128 + ko) ^ SW1(col)] = *(const bf16x8*)(w0k + col * 128 + ko);
    }
    __syncthreads();

    f32x4 akv[4][4] = {};
    float ask[4] = {0.f, 0.f, 0.f, 0.f};

    for (int g = cb * 8 + w; g < NG32; g += 176) {
      const int rbase = g * 32;
      bf16x8 ax[2][4];
      #pragma unroll
      for (int jt = 0; jt < 2; ++jt)
        #pragma unroll
        for (int ks = 0; ks < 4; ++ks)
          ax[jt][ks] = *(const bf16x8*)(Xb + (size_t)(rbase + jt * 16 + l15) * 128 + ks * 32 + lg * 8);
      float mv[2][4];
      #pragma unroll
      for (int rt = 0; rt < 2; ++rt)
        #pragma unroll
        for (int r = 0; r < 4; ++r) {
          int row = rbase + rt * 16 + lg * 4 + r;
          mv[rt][r] = (row < NPTS) ? mask[row] : 0.f;
        }

      // ---------- K pass (W0 from LDS) ----------
      {
        f32x4 acc2[2][4] = {};  // [rt(xrow)][f(outcol)]  (normal layer2)
        #pragma unroll
        for (int c = 0; c < 4; ++c) {
          f32x4 a1[4][2] = {};
          #pragma unroll
          for (int ks = 0; ks < 4; ++ks) {
            bf16x8 wa[4];
            #pragma unroll
            for (int fi = 0; fi < 4; ++fi) {
              int col = c * 64 + fi * 16 + l15;
              wa[fi] = *(const bf16x8*)&sW0[(col * 128 + ks * 32 + lg * 8) ^ SW1(col)];
            }
            #pragma unroll
            for (int fi = 0; fi < 4; ++fi)
              #pragma unroll
              for (int jt = 0; jt < 2; ++jt)
                a1[fi][jt] = MFMA16(wa[fi], ax[jt][ks], a1[fi][jt]);
          }
          #pragma unroll
          for (int fi = 0; fi < 4; ++fi) {
            f32x4 b0 = *(const f32x4*)&bk0[h * 256 + c * 64 + fi * 16 + lg * 4];
            #pragma unroll
            for (int jt = 0; jt < 2; ++jt) {
              bf16x4 hv;
              #pragma unroll
              for (int r = 0; r < 4; ++r) {
                float v = a1[fi][jt][r] + b0[r];
                hv[r] = (__bf16)(v > 0.f ? v : 0.f);
              }
              int row = jt * 16 + l15;
              *(bf16x4*)&sHV[(row * 64 + fi * 16 + lg * 4) ^ SW1(row)] = hv;
            }
          }
          #pragma unroll
          for (int ks2 = 0; ks2 < 2; ++ks2) {
            bf16x8 ah[2], wb[4];
            #pragma unroll
            for (int rt = 0; rt < 2; ++rt) {
              int row = rt * 16 + l15;
              ah[rt] = *(const bf16x8*)&sHV[(row * 64 + ks2 * 32 + lg * 8) ^ SW1(row)];
            }
            #pragma unroll
            for (int f = 0; f < 4; ++f)
              wb[f] = *(const bf16x8*)(w1k + (size_t)(f * 16 + l15) * 256 + c * 64 + ks2 * 32 + lg * 8);
            #pragma unroll
            for (int rt = 0; rt < 2; ++rt)
              #pragma unroll
              for (int f = 0; f < 4; ++f)
                acc2[rt][f] = MFMA16(ah[rt], wb[f], acc2[rt][f]);
          }
        }
        // kk epilogue -> sKK (transposed [kq][x], packed 8B)
        #pragma unroll
        for (int f = 0; f < 4; ++f) {
          float b1s = bk1[h * 64 + f * 16 + l15];
          #pragma unroll
          for (int rt = 0; rt < 2; ++rt) {
            bf16x4 k4;
            #pragma unroll
            for (int r = 0; r < 4; ++r) {
              int row = rbase + rt * 16 + lg * 4 + r;
              float v = (acc2[rt][f][r] + b1s) * mv[rt][r];
              float pk = (row < NPTS) ? (v > 0.f ? v + 1.f : __expf(v)) : 0.f;
              k4[r] = (__bf16)pk;
            }
            *(bf16x4*)&sKK[(f * 16 + l15) * 40 + rt * 16 + lg * 4] = k4;
          }
        }
      }

      // ---------- V pass (W0 from global/L2) ----------
      {
        f32x4 acc2[2][4] = {};
        #pragma unroll
        for (int c = 0; c < 4; ++c) {
          f32x4 a1[4][2] = {};
          #pragma unroll
          for (int ks = 0; ks < 4; ++ks) {
            bf16x8 wa[4];
            #pragma unroll
            for (int fi = 0; fi < 4; ++fi)
              wa[fi] = *(const bf16x8*)(w0v + (size_t)(c * 64 + fi * 16 + l15) * 128 + ks * 32 + lg * 8);
            #pragma unroll
            for (int fi = 0; fi < 4; ++fi)
              #pragma unroll
              for (int jt = 0; jt < 2; ++jt)
                a1[fi][jt] = MFMA16(wa[fi], ax[jt][ks], a1[fi][jt]);
          }
          #pragma unroll
          for (int fi = 0; fi < 4; ++fi) {
            f32x4 b0 = *(const f32x4*)&bv0[h * 256 + c * 64 + fi * 16 + lg * 4];
            #pragma unroll
            for (int jt = 0; jt < 2; ++jt) {
              bf16x4 hv;
              #pragma unroll
              for (int r = 0; r < 4; ++r) {
                float v = a1[fi][jt][r] + b0[r];
                hv[r] = (__bf16)(v > 0.f ? v : 0.f);
              }
              int row = jt * 16 + l15;
              *(bf16x4*)&sHV[(row * 64 + fi * 16 + lg * 4) ^ SW1(row)] = hv;
            }
          }
          #pragma unroll
          for (int ks2 = 0; ks2 < 2; ++ks2) {
            bf16x8 ah[2], wb[4];
            #pragma unroll
            for (int rt = 0; rt < 2; ++rt) {
              int row = rt * 16 + l15;
              ah[rt] = *(const bf16x8*)&sHV[(row * 64 + ks2 * 32 + lg * 8) ^ SW1(row)];
            }
            #pragma unroll
            for (int f = 0; f < 4; ++f)
              wb[f] = *(const bf16x8*)(w1v + (size_t)(f * 16 + l15) * 256 + c * 64 + ks2 * 32 + lg * 8);
            #pragma unroll
            for (int rt = 0; rt < 2; ++rt)
              #pragma unroll
              for (int f = 0; f < 4; ++f)
                acc2[rt][f] = MFMA16(ah[rt], wb[f], acc2[rt][f]);
          }
        }
        // v epilogue -> sVT (aliases sHV; all sH reads for this iter are done)
        #pragma unroll
        for (int f = 0; f < 4; ++f) {
          float b1s = bv1[h * 64 + f * 16 + l15];
          #pragma unroll
          for (int rt = 0; rt < 2; ++rt) {
            bf16x4 v4;
            #pragma unroll
            for (int r = 0; r < 4; ++r) {
              float v = (acc2[rt][f][r] + b1s) * mv[rt][r];
              v4[r] = (__bf16)v;
            }
            *(bf16x4*)&sHV[(f * 16 + l15) * 40 + rt * 16 + lg * 4] = v4;
          }
        }
      }

      // ---------- kv outer product (K=32) + sumk ----------
      bf16x8 akk[4], bvt[4];
      #pragma unroll
      for (int fi = 0; fi < 4; ++fi)
        akk[fi] = *(const bf16x8*)&sKK[(fi * 16 + l15) * 40 + lg * 8];
      #pragma unroll
      for (int fj = 0; fj < 4; ++fj)
        bvt[fj] = *(const bf16x8*)&sHV[(fj * 16 + l15) * 40 + lg * 8];
      #pragma unroll
      for (int fi = 0; fi < 4; ++fi)
        #pragma unroll
        for (int fj = 0; fj < 4; ++fj)
          akv[fi][fj] = MFMA16(akk[fi], bvt[fj], akv[fi][fj]);
      #pragma unroll
      for (int fi = 0; fi < 4; ++fi) {
        float s = 0.f;
        #pragma unroll
        for (int e = 0; e < 8; ++e) s += (float)akk[fi][e];
        s += __shfl_xor(s, 16);
        s += __shfl_xor(s, 32);
        ask[fi] += s;
      }
    }

    // flush: per-wave kv partial to parts buffer (no fp atomics on kv)
    float* mypart = kvp + ((size_t)(h * 22 + cb) * 8 + w) * 4096;
    #pragma unroll
    for (int fi = 0; fi < 4; ++fi)
      #pragma unroll
      for (int fj = 0; fj < 4; ++fj)
        #pragma unroll
        for (int r = 0; r < 4; ++r)
          mypart[(fi * 16 + lg * 4 + r) * 64 + fj * 16 + l15] = akv[fi][fj][r];
    if (lg == 0) {
      #pragma unroll
      for (int fi = 0; fi < 4; ++fi)
        atomicAdd(&sumk[h * 64 + fi * 16 + l15], ask[fi]);
    }
  }
}

// ---------- reduce kv parts -> kvTe bf16 [8][j][k] ----------
__global__ void k_kvt(const float* __restrict__ kvp, __bf16* __restrict__ kvTe) {
  int i = blockIdx.x * 256 + threadIdx.x;
  if (i >= 32768) return;
  int h = i >> 12, j = (i >> 6) & 63, k = i & 63;
  const float* base = kvp + (size_t)h * 176 * 4096 + k * 64 + j;
  float s = 0.f;
  for (int p = 0; p < 176; ++p) s += base[(size_t)p * 4096];
  kvTe[i] = (__bf16)s;
}

// ---------- attention normalize + psi MLP (unchanged from round 2) ----------
__global__ __launch_bounds__(512, 2) void k_cd(
    const float* __restrict__ mask, const __bf16* __restrict__ qk_ws,
    const __bf16* __restrict__ kvTe, const float* __restrict__ sumk,
    const __bf16* __restrict__ Wp0t, const __bf16* __restrict__ Wp1t,
    const float* __restrict__ bp0, const float* __restrict__ bp1,
    float* __restrict__ out)
{
  __shared__ __bf16 sWp0c[16384];
  __shared__ __bf16 sCat[8192];
  __shared__ __bf16 sH2[32768];
  __shared__ float sSumk[512];

  const int tid = threadIdx.x, w = tid >> 6, lane = tid & 63, l15 = lane & 15, lg = lane >> 4;
  const int rbase = blockIdx.x * 128 + w * 16;
  __bf16* myCat = sCat + w * 1024;
  __bf16* myH2 = sH2 + w * 4096;

  sSumk[tid] = sumk[tid];

  f32x4 acc1[16] = {};
  for (int h = 0; h < 8; ++h) {
    __syncthreads();
    #pragma unroll
    for (int i = 0; i < 4; ++i) {
      int u = tid + i * 512;
      int col = u >> 3, koff = (u & 7) << 3;
      *(bf16x8*)&sWp0c[(col * 64 + koff) ^ SW1(col)] =
          *(const bf16x8*)(Wp0t + (size_t)col * 512 + h * 64 + koff);
    }
    __syncthreads();
    bf16x8 axq[2];
    #pragma unroll
    for (int ks = 0; ks < 2; ++ks)
      axq[ks] = *(const bf16x8*)(qk_ws + ((size_t)h * NPAD2 + rbase + l15) * 64 + ks * 32 + lg * 8);
    f32x4 accn[4] = {};
    #pragma unroll
    for (int ks = 0; ks < 2; ++ks)
      #pragma unroll
      for (int f = 0; f < 4; ++f) {
        bf16x8 bv = *(const bf16x8*)(kvTe + ((size_t)h * 64 + f * 16 + l15) * 64 + ks * 32 + lg * 8);
        accn[f] = MFMA16(axq[ks], bv, accn[f]);
      }
    float p = 0.f;
    #pragma unroll
    for (int ks = 0; ks < 2; ++ks)
      #pragma unroll
      for (int e = 0; e < 8; ++e)
        p += (float)axq[ks][e] * sSumk[h * 64 + ks * 32 + lg * 8 + e];
    p += __shfl_xor(p, 16);
    p += __shfl_xor(p, 32);
    float dinv[4];
    #pragma unroll
    for (int r = 0; r < 4; ++r) {
      float d = __shfl(p, (lane & 48) + ((lane >> 4) << 2) + r);
      d = (d == 0.f) ? 1e-6f : d;
      dinv[r] = 1.f / d;
    }
    #pragma unroll
    for (int f = 0; f < 4; ++f)
      #pragma unroll
      for (int r = 0; r < 4; ++r) {
        int row = lg * 4 + r;
        myCat[(row * 64 + f * 16 + l15) ^ SW1(row)] = (__bf16)(accn[f][r] * dinv[r]);
      }
    #pragma unroll
    for (int ks2 = 0; ks2 < 2; ++ks2) {
      bf16x8 aC = *(const bf16x8*)&myCat[(l15 * 64 + ks2 * 32 + lg * 8) ^ SW1(l15)];
      #pragma unroll
      for (int f = 0; f < 16; ++f) {
        bf16x8 bw = *(const bf16x8*)&sWp0c[((f * 16 + l15) * 64 + ks2 * 32 + lg * 8) ^ SW1(l15)];
        acc1[f] = MFMA16(aC, bw, acc1[f]);
      }
    }
  }
  #pragma unroll
  for (int f = 0; f < 16; ++f) {
    float bias = bp0[f * 16 + l15];
    #pragma unroll
    for (int r = 0; r < 4; ++r) {
      int row = lg * 4 + r;
      float val = acc1[f][r] + bias;
      val = val > 0.f ? val : 0.f;
      myH2[(row * 256 + f * 16 + l15) ^ SW1(row)] = (__bf16)val;
    }
  }
  f32x4 acc2[8] = {};
  #pragma unroll
  for (int ks = 0; ks < 8; ++ks) {
    bf16x8 aH = *(const bf16x8*)&myH2[(l15 * 256 + ks * 32 + lg * 8) ^ SW1(l15)];
    #pragma unroll
    for (int f = 0; f < 8; ++f) {
      bf16x8 bw = *(const bf16x8*)(Wp1t + (size_t)(f * 16 + l15) * 256 + ks * 32 + lg * 8);
      acc2[f] = MFMA16(aH, bw, acc2[f]);
    }
  }
  float mvr[4];
  #pragma unroll
  for (int r = 0; r < 4; ++r) {
    int grow = rbase + lg * 4 + r;
    mvr[r] = (grow < NPTS) ? mask[grow] : 0.f;
  }
  #pragma unroll
  for (int f = 0; f < 8; ++f) {
    int col = f * 16 + l15;
    float bias = bp1[col];
    #pragma unroll
    for (int r = 0; r < 4; ++r) {
      int grow = rbase + lg * 4 + r;
      if (grow < NPTS) out[(size_t)grow * 128 + col] = (acc2[f][r] + bias) * mvr[r];
    }
  }
}

extern "C" void kernel_launch(void* const* d_in, const int* in_sizes, int n_in,
                              void* d_out, int out_size, void* d_ws, size_t ws_size,
                              hipStream_t stream) {
  const float* coords = (const float*)d_in[0];
  const float* mask   = (const float*)d_in[1];
  const float* Wq0 = (const float*)d_in[2];
  const float* bq0 = (const float*)d_in[3];
  const float* Wq1 = (const float*)d_in[4];
  const float* bq1 = (const float*)d_in[5];
  const float* Wk0 = (const float*)d_in[6];
  const float* bk0 = (const float*)d_in[7];
  const float* Wk1 = (const float*)d_in[8];
  const float* bk1 = (const float*)d_in[9];
  const float* Wv0 = (const float*)d_in[10];
  const float* bv0 = (const float*)d_in[11];
  const float* Wv1 = (const float*)d_in[12];
  const float* bv1 = (const float*)d_in[13];
  const float* Wp0 = (const float*)d_in[14];
  const float* bp0 = (const float*)d_in[15];
  const float* Wp1 = (const float*)d_in[16];
  const float* bp1 = (const float*)d_in[17];
  float* out = (float*)d_out;

  char* p = (char*)d_ws;
  __bf16* qk_ws = (__bf16*)p; p += (size_t)8 * NPAD2 * 64 * 2;     // 102,498,304
  __bf16* Xb    = (__bf16*)p; p += (size_t)NPAD2 * 128 * 2;        //  25,624,576
  __bf16* W0t   = (__bf16*)p; p += (size_t)24 * 32768 * 2;         //   1,572,864
  __bf16* W1t   = (__bf16*)p; p += (size_t)24 * 16384 * 2;         //     786,432
  __bf16* Wp0t  = (__bf16*)p; p += (size_t)256 * 512 * 2;          //     262,144
  __bf16* Wp1t  = (__bf16*)p; p += (size_t)128 * 256 * 2;          //      65,536
  float*  kvp   = (float*)p;  p += (size_t)8 * 176 * 4096 * 4;     //  23,068,672
  float*  sumk  = (float*)p;  p += (size_t)512 * 4;                //       2,048
  __bf16* kvTe  = (__bf16*)p; p += (size_t)8 * 64 * 64 * 2;        //      65,536

  k_prep_x<<<2048, 256, 0, stream>>>(coords, Xb);
  k_prep_w<<<1024, 256, 0, stream>>>(Wq0, Wk0, Wv0, Wq1, Wk1, Wv1, Wp0, Wp1,
                                     W0t, W1t, Wp0t, Wp1t, sumk);
  k_mlp<<<256, 512, 0, stream>>>(Xb, mask, W0t, W1t, bq0, bq1, bk0, bk1, bv0, bv1,
                                 qk_ws, kvp, sumk);
  k_kvt<<<128, 256, 0, stream>>>(kvp, kvTe);
  k_cd<<<782, 512, 0, stream>>>(mask, qk_ws, kvTe, sumk, Wp0t, Wp1t, bp0, bp1, out);
}

// Round 4
// 860.665 us; speedup vs baseline: 3.1366x; 2.2866x over previous
//
#include <hip/hip_runtime.h>
#include <hip/hip_bf16.h>
#include <math.h>

// N=100000, D=128, H=8, HID=256, QK=64, V=64, PSI_HID=256, OUT=128
#define NPTS 100000
#define NPAD 100352           // 448 groups * 224 rows = 784 * 128
#define NGRP 448

typedef __bf16 bf16x8 __attribute__((ext_vector_type(8)));
typedef __bf16 bf16x4 __attribute__((ext_vector_type(4)));
typedef float f32x4 __attribute__((ext_vector_type(4)));

#define MFMA16(a,b,c) __builtin_amdgcn_mfma_f32_16x16x32_bf16((a),(b),(c),0,0,0)
#define SW(row) (((row)&7)<<3)

// ---------- prep: coordinates -> bf16, zero-padded to NPAD ----------
__global__ void k_prep_x(const float* __restrict__ coords, __bf16* __restrict__ Xb) {
  const int total = NPAD * 16;
  for (int c = blockIdx.x * 256 + threadIdx.x; c < total; c += gridDim.x * 256) {
    int row = c >> 4;
    int e8 = (c & 15) << 3;
    bf16x8 v = {};
    if (row < NPTS) {
      const float4* p = (const float4*)(coords + (size_t)row * 128 + e8);
      float4 f0 = p[0], f1 = p[1];
      v[0] = (__bf16)f0.x; v[1] = (__bf16)f0.y; v[2] = (__bf16)f0.z; v[3] = (__bf16)f0.w;
      v[4] = (__bf16)f1.x; v[5] = (__bf16)f1.y; v[6] = (__bf16)f1.z; v[7] = (__bf16)f1.w;
    }
    *(bf16x8*)(Xb + (size_t)row * 128 + e8) = v;
  }
}

// ---------- prep: weights cast/transpose ----------
__global__ void k_prep_w(const float* __restrict__ Wq0, const float* __restrict__ Wk0,
                         const float* __restrict__ Wv0, const float* __restrict__ Wq1,
                         const float* __restrict__ Wk1, const float* __restrict__ Wv1,
                         const float* __restrict__ Wp0, const float* __restrict__ Wp1,
                         __bf16* __restrict__ W0t, __bf16* __restrict__ W1t,
                         __bf16* __restrict__ Wp0t, __bf16* __restrict__ Wp1t) {
  for (int i = blockIdx.x * 256 + threadIdx.x; i < 1343488; i += gridDim.x * 256) {
    if (i < 786432) {                      // W0t [24][256 hid][128 d]
      int g = i >> 15, j = i & 32767;
      int mat = g >> 3, h = g & 7, mcol = j >> 7, k = j & 127;
      const float* src = (mat == 0) ? Wq0 : (mat == 1) ? Wk0 : Wv0;
      W0t[i] = (__bf16)src[h * 32768 + k * 256 + mcol];
    } else if (i < 1179648) {              // W1t [24][64 o][256 hid]
      int t = i - 786432;
      int g = t >> 14, j = t & 16383;
      int mat = g >> 3, h = g & 7, ocol = j >> 8, k = j & 255;
      const float* src = (mat == 0) ? Wq1 : (mat == 1) ? Wk1 : Wv1;
      W1t[t] = (__bf16)src[h * 16384 + k * 64 + ocol];
    } else if (i < 1310720) {              // Wp0t [256][512]
      int t = i - 1179648;
      int col = t >> 9, k = t & 511;
      Wp0t[t] = (__bf16)Wp0[k * 256 + col];
    } else {                               // Wp1t [128][256]
      int t = i - 1310720;
      int col = t >> 8, k = t & 255;
      Wp1t[t] = (__bf16)Wp1[k * 128 + col];
    }
  }
}

// ---------- staging: one (W0 row-half + W1 k-half) -> LDS, swizzled ----------
__device__ __forceinline__ void stage_half(
    __bf16* __restrict__ sW0, __bf16* __restrict__ sW1,
    const __bf16* __restrict__ w0, const __bf16* __restrict__ w1,
    int half, int tid)
{
  #pragma unroll
  for (int i = 0; i < 5; ++i) {
    int u = tid + i * 448;
    if (u < 2048) {
      int r = u >> 4, k8 = (u & 15) << 3;
      *(bf16x8*)&sW0[(r * 128 + k8) ^ SW(r)] =
          *(const bf16x8*)(w0 + (size_t)(half * 128 + r) * 128 + k8);
    }
  }
  #pragma unroll
  for (int i = 0; i < 3; ++i) {
    int u = tid + i * 448;
    if (u < 1024) {
      int o = u >> 4, k8 = (u & 15) << 3;
      *(bf16x8*)&sW1[(o * 128 + k8) ^ SW(o)] =
          *(const bf16x8*)(w1 + (size_t)o * 256 + half * 128 + k8);
    }
  }
}

// ---------- two-layer MLP over one weight-half (128 hidden cols) ----------
// SWAP=true: layer2 output transposed (lane = x-row) for packed row-major stores.
template<bool SWAP>
__device__ __forceinline__ void compute_half(
    const __bf16* __restrict__ sW0, const __bf16* __restrict__ sW1,
    __bf16* __restrict__ myHid, const bf16x8 (&ax)[2][4],
    const float* __restrict__ b0h, int l15, int lg, f32x4* acc2)
{
  #pragma unroll
  for (int cg = 0; cg < 2; ++cg) {
    f32x4 a1[4][2] = {};
    #pragma unroll
    for (int ks = 0; ks < 4; ++ks) {
      bf16x8 wa[4];
      #pragma unroll
      for (int fi = 0; fi < 4; ++fi) {
        int hl = cg * 64 + fi * 16 + l15;
        wa[fi] = *(const bf16x8*)&sW0[(hl * 128 + ks * 32 + lg * 8) ^ SW(hl)];
      }
      #pragma unroll
      for (int fi = 0; fi < 4; ++fi)
        #pragma unroll
        for (int jt = 0; jt < 2; ++jt)
          a1[fi][jt] = MFMA16(wa[fi], ax[jt][ks], a1[fi][jt]);
    }
    // bias + relu -> hidden [2 jt][16 x][64 hid], packed bf16x4
    #pragma unroll
    for (int fi = 0; fi < 4; ++fi) {
      f32x4 b0 = *(const f32x4*)&b0h[cg * 64 + fi * 16 + lg * 4];
      #pragma unroll
      for (int jt = 0; jt < 2; ++jt) {
        bf16x4 hv;
        #pragma unroll
        for (int r = 0; r < 4; ++r) {
          float v = a1[fi][jt][r] + b0[r];
          hv[r] = (__bf16)(v > 0.f ? v : 0.f);
        }
        *(bf16x4*)&myHid[jt * 1024 + ((l15 * 64 + fi * 16 + lg * 4) ^ SW(l15))] = hv;
      }
    }
    // layer2 partial over this 64-hid chunk
    #pragma unroll
    for (int ks2 = 0; ks2 < 2; ++ks2) {
      bf16x8 hb[2], wf[4];
      #pragma unroll
      for (int jt = 0; jt < 2; ++jt)
        hb[jt] = *(const bf16x8*)&myHid[jt * 1024 + ((l15 * 64 + ks2 * 32 + lg * 8) ^ SW(l15))];
      #pragma unroll
      for (int f = 0; f < 4; ++f) {
        int o = f * 16 + l15;
        wf[f] = *(const bf16x8*)&sW1[(o * 128 + cg * 64 + ks2 * 32 + lg * 8) ^ SW(o)];
      }
      #pragma unroll
      for (int f = 0; f < 4; ++f)
        #pragma unroll
        for (int jt = 0; jt < 2; ++jt) {
          if (SWAP) acc2[f * 2 + jt] = MFMA16(wf[f], hb[jt], acc2[f * 2 + jt]);
          else      acc2[jt * 4 + f] = MFMA16(hb[jt], wf[f], acc2[jt * 4 + f]);
        }
    }
  }
}

// ---------- fused QKV MLPs + kv/sumk partials ----------
// 256 blocks x 448 thr (7 waves). X-stationary: each group = 224 rows in regs.
__global__ __launch_bounds__(448) void k_mlp(
    const __bf16* __restrict__ Xb, const float* __restrict__ mask,
    const __bf16* __restrict__ W0t, const __bf16* __restrict__ W1t,
    const float* __restrict__ bq0, const float* __restrict__ bq1,
    const float* __restrict__ bk0, const float* __restrict__ bk1,
    const float* __restrict__ bv0, const float* __restrict__ bv1,
    __bf16* __restrict__ qk_ws, float* __restrict__ parts)
{
  __shared__ __bf16 sW0[128 * 128];   // 32KB: W0 row-half (hid 128 x d 128)
  __shared__ __bf16 sW1[64 * 128];    // 16KB: W1 k-half  (o 64 x hid 128)
  __shared__ __bf16 sKT[64 * 224];    // 28KB: kk^T [kq][x]
  __shared__ __bf16 sVT[64 * 224];    // 28KB: v^T  [j][x]
  __shared__ __bf16 sHid[7 * 2048];   // 28KB: per-wave hidden [2][16][64]

  const int tid = threadIdx.x, w = tid >> 6, lane = tid & 63;
  const int l15 = lane & 15, lg = lane >> 4;
  __bf16* myHid = sHid + w * 2048;

  for (int g = blockIdx.x; g < NGRP; g += 256) {
    const int base = g * 224 + w * 32;
    const bool first = (g == (int)blockIdx.x);

    // X rows in registers (read once); masks
    bf16x8 ax[2][4];
    #pragma unroll
    for (int jt = 0; jt < 2; ++jt)
      #pragma unroll
      for (int ks = 0; ks < 4; ++ks)
        ax[jt][ks] = *(const bf16x8*)(Xb + (size_t)(base + jt * 16 + l15) * 128 + ks * 32 + lg * 8);
    float mq[2];
    f32x4 mv[2];
    #pragma unroll
    for (int jt = 0; jt < 2; ++jt) {
      int rq = base + jt * 16 + l15;
      mq[jt] = (rq < NPTS) ? mask[rq] : 0.f;
      int rv = base + jt * 16 + lg * 4;
      if (rv < NPTS) mv[jt] = *(const f32x4*)&mask[rv];
      else           mv[jt] = f32x4{0.f, 0.f, 0.f, 0.f};
    }

    for (int h = 0; h < 8; ++h) {
      #pragma unroll 1
      for (int m = 0; m < 3; ++m) {
        const __bf16* w0 = W0t + (size_t)(m * 8 + h) * 32768;
        const __bf16* w1 = W1t + (size_t)(m * 8 + h) * 16384;
        const float* b0 = (m == 0) ? bq0 : (m == 1) ? bk0 : bv0;
        f32x4 acc2[8] = {};
        #pragma unroll 1
        for (int half = 0; half < 2; ++half) {
          __syncthreads();                     // prev readers of sW0/sW1 done
          stage_half(sW0, sW1, w0, w1, half, tid);
          __syncthreads();
          if (m == 0) compute_half<true >(sW0, sW1, myHid, ax, b0 + h * 256 + half * 128, l15, lg, acc2);
          else        compute_half<false>(sW0, sW1, myHid, ax, b0 + h * 256 + half * 128, l15, lg, acc2);
        }
        if (m == 0) {
          // phi(q) -> qk_ws, packed row-major (swapped layout: lane = x-row)
          #pragma unroll
          for (int ft = 0; ft < 4; ++ft) {
            f32x4 b1 = *(const f32x4*)&bq1[h * 64 + ft * 16 + lg * 4];
            #pragma unroll
            for (int jt = 0; jt < 2; ++jt) {
              bf16x4 qv;
              f32x4 a = acc2[ft * 2 + jt];
              #pragma unroll
              for (int r = 0; r < 4; ++r) {
                float v = (a[r] + b1[r]) * mq[jt];
                qv[r] = (__bf16)(v > 0.f ? v + 1.f : __expf(v));
              }
              *(bf16x4*)(qk_ws + ((size_t)h * NPAD + base + jt * 16 + l15) * 64 + ft * 16 + lg * 4) = qv;
            }
          }
        } else if (m == 1) {
          // phi(k), pad rows forced to 0 -> sKT [kq][x]
          #pragma unroll
          for (int f = 0; f < 4; ++f) {
            float b1 = bk1[h * 64 + f * 16 + l15];
            #pragma unroll
            for (int jt = 0; jt < 2; ++jt) {
              bf16x4 k4;
              f32x4 a = acc2[jt * 4 + f];
              #pragma unroll
              for (int r = 0; r < 4; ++r) {
                int row = base + jt * 16 + lg * 4 + r;
                float v = (a[r] + b1) * mv[jt][r];
                k4[r] = (__bf16)((row < NPTS) ? (v > 0.f ? v + 1.f : __expf(v)) : 0.f);
              }
              *(bf16x4*)&sKT[(f * 16 + l15) * 224 + w * 32 + jt * 16 + lg * 4] = k4;
            }
          }
        } else {
          // v -> sVT [j][x]
          #pragma unroll
          for (int f = 0; f < 4; ++f) {
            float b1 = bv1[h * 64 + f * 16 + l15];
            #pragma unroll
            for (int jt = 0; jt < 2; ++jt) {
              bf16x4 v4;
              f32x4 a = acc2[jt * 4 + f];
              #pragma unroll
              for (int r = 0; r < 4; ++r)
                v4[r] = (__bf16)((a[r] + b1) * mv[jt][r]);
              *(bf16x4*)&sVT[(f * 16 + l15) * 224 + w * 32 + jt * 16 + lg * 4] = v4;
            }
          }
        }
      }
      __syncthreads();   // sKT/sVT complete from all waves
      // kv tiles: 16 16x16 tiles over 7 waves, K=224; accumulate into parts
      float* dst = parts + ((size_t)blockIdx.x * 8 + h) * 4160;
      for (int t = w; t < 16; t += 7) {
        int fi = t >> 2, fj = t & 3;
        f32x4 acc = {};
        #pragma unroll
        for (int ks = 0; ks < 7; ++ks) {
          bf16x8 a = *(const bf16x8*)&sKT[(fi * 16 + l15) * 224 + ks * 32 + lg * 8];
          bf16x8 b = *(const bf16x8*)&sVT[(fj * 16 + l15) * 224 + ks * 32 + lg * 8];
          acc = MFMA16(a, b, acc);
        }
        #pragma unroll
        for (int r = 0; r < 4; ++r) {
          size_t idx = (size_t)(fi * 16 + lg * 4 + r) * 64 + fj * 16 + l15;
          dst[idx] = first ? acc[r] : dst[idx] + acc[r];
        }
      }
      // sumk partials (waves 0..3, 16 kq each)
      if (w < 4) {
        float s = 0.f;
        #pragma unroll
        for (int c = 0; c < 7; ++c) {
          bf16x8 kk = *(const bf16x8*)&sKT[(w * 16 + l15) * 224 + lg * 56 + c * 8];
          #pragma unroll
          for (int e = 0; e < 8; ++e) s += (float)kk[e];
        }
        s += __shfl_xor(s, 16);
        s += __shfl_xor(s, 32);
        if (lg == 0) {
          size_t idx = 4096 + w * 16 + l15;
          dst[idx] = first ? s : dst[idx] + s;
        }
      }
    }
  }
}

// ---------- reduce parts -> kvTe bf16 [8][j][k], sumk f32 [512] ----------
__global__ void k_kvt(const float* __restrict__ parts, __bf16* __restrict__ kvTe,
                      float* __restrict__ sumk) {
  int i = blockIdx.x * 256 + threadIdx.x;
  if (i < 32768) {
    int h = i >> 12, rem = i & 4095;
    const float* src = parts + h * 4160 + rem;
    float s = 0.f;
    #pragma unroll 8
    for (int b = 0; b < 256; ++b) s += src[(size_t)b * 33280];
    int kq = rem >> 6, j = rem & 63;
    kvTe[((size_t)h * 64 + j) * 64 + kq] = (__bf16)s;
  } else if (i < 33280) {
    int t = i - 32768;
    const float* src = parts + (t >> 6) * 4160 + 4096 + (t & 63);
    float s = 0.f;
    #pragma unroll 8
    for (int b = 0; b < 256; ++b) s += src[(size_t)b * 33280];
    sumk[t] = s;
  }
}

// ---------- attention normalize + psi MLP ----------
__global__ __launch_bounds__(512, 2) void k_cd(
    const float* __restrict__ mask, const __bf16* __restrict__ qk_ws,
    const __bf16* __restrict__ kvTe, const float* __restrict__ sumk,
    const __bf16* __restrict__ Wp0t, const __bf16* __restrict__ Wp1t,
    const float* __restrict__ bp0, const float* __restrict__ bp1,
    float* __restrict__ out)
{
  __shared__ __bf16 sWp0c[16384];
  __shared__ __bf16 sCat[8192];
  __shared__ __bf16 sH2[32768];
  __shared__ float sSumk[512];

  const int tid = threadIdx.x, w = tid >> 6, lane = tid & 63, l15 = lane & 15, lg = lane >> 4;
  const int rbase = blockIdx.x * 128 + w * 16;
  __bf16* myCat = sCat + w * 1024;
  __bf16* myH2 = sH2 + w * 4096;

  sSumk[tid] = sumk[tid];

  f32x4 acc1[16] = {};
  for (int h = 0; h < 8; ++h) {
    __syncthreads();
    #pragma unroll
    for (int i = 0; i < 4; ++i) {
      int u = tid + i * 512;
      int col = u >> 3, koff = (u & 7) << 3;
      *(bf16x8*)&sWp0c[(col * 64 + koff) ^ SW(col)] =
          *(const bf16x8*)(Wp0t + (size_t)col * 512 + h * 64 + koff);
    }
    __syncthreads();
    bf16x8 axq[2];
    #pragma unroll
    for (int ks = 0; ks < 2; ++ks)
      axq[ks] = *(const bf16x8*)(qk_ws + ((size_t)h * NPAD + rbase + l15) * 64 + ks * 32 + lg * 8);
    f32x4 accn[4] = {};
    #pragma unroll
    for (int ks = 0; ks < 2; ++ks)
      #pragma unroll
      for (int f = 0; f < 4; ++f) {
        bf16x8 bv = *(const bf16x8*)(kvTe + ((size_t)h * 64 + f * 16 + l15) * 64 + ks * 32 + lg * 8);
        accn[f] = MFMA16(axq[ks], bv, accn[f]);
      }
    float p = 0.f;
    #pragma unroll
    for (int ks = 0; ks < 2; ++ks)
      #pragma unroll
      for (int e = 0; e < 8; ++e)
        p += (float)axq[ks][e] * sSumk[h * 64 + ks * 32 + lg * 8 + e];
    p += __shfl_xor(p, 16);
    p += __shfl_xor(p, 32);
    float dinv[4];
    #pragma unroll
    for (int r = 0; r < 4; ++r) {
      float d = __shfl(p, (lane & 48) + ((lane >> 4) << 2) + r);
      d = (d == 0.f) ? 1e-6f : d;
      dinv[r] = 1.f / d;
    }
    #pragma unroll
    for (int f = 0; f < 4; ++f)
      #pragma unroll
      for (int r = 0; r < 4; ++r) {
        int row = lg * 4 + r;
        myCat[(row * 64 + f * 16 + l15) ^ SW(row)] = (__bf16)(accn[f][r] * dinv[r]);
      }
    #pragma unroll
    for (int ks2 = 0; ks2 < 2; ++ks2) {
      bf16x8 aC = *(const bf16x8*)&myCat[(l15 * 64 + ks2 * 32 + lg * 8) ^ SW(l15)];
      #pragma unroll
      for (int f = 0; f < 16; ++f) {
        bf16x8 bw = *(const bf16x8*)&sWp0c[((f * 16 + l15) * 64 + ks2 * 32 + lg * 8) ^ SW(l15)];
        acc1[f] = MFMA16(aC, bw, acc1[f]);
      }
    }
  }
  #pragma unroll
  for (int f = 0; f < 16; ++f) {
    float bias = bp0[f * 16 + l15];
    #pragma unroll
    for (int r = 0; r < 4; ++r) {
      int row = lg * 4 + r;
      float val = acc1[f][r] + bias;
      val = val > 0.f ? val : 0.f;
      myH2[(row * 256 + f * 16 + l15) ^ SW(row)] = (__bf16)val;
    }
  }
  f32x4 acc2[8] = {};
  #pragma unroll
  for (int ks = 0; ks < 8; ++ks) {
    bf16x8 aH = *(const bf16x8*)&myH2[(l15 * 256 + ks * 32 + lg * 8) ^ SW(l15)];
    #pragma unroll
    for (int f = 0; f < 8; ++f) {
      bf16x8 bw = *(const bf16x8*)(Wp1t + (size_t)(f * 16 + l15) * 256 + ks * 32 + lg * 8);
      acc2[f] = MFMA16(aH, bw, acc2[f]);
    }
  }
  float mvr[4];
  #pragma unroll
  for (int r = 0; r < 4; ++r) {
    int grow = rbase + lg * 4 + r;
    mvr[r] = (grow < NPTS) ? mask[grow] : 0.f;
  }
  #pragma unroll
  for (int f = 0; f < 8; ++f) {
    int col = f * 16 + l15;
    float bias = bp1[col];
    #pragma unroll
    for (int r = 0; r < 4; ++r) {
      int grow = rbase + lg * 4 + r;
      if (grow < NPTS) out[(size_t)grow * 128 + col] = (acc2[f][r] + bias) * mvr[r];
    }
  }
}

extern "C" void kernel_launch(void* const* d_in, const int* in_sizes, int n_in,
                              void* d_out, int out_size, void* d_ws, size_t ws_size,
                              hipStream_t stream) {
  const float* coords = (const float*)d_in[0];
  const float* mask   = (const float*)d_in[1];
  const float* Wq0 = (const float*)d_in[2];
  const float* bq0 = (const float*)d_in[3];
  const float* Wq1 = (const float*)d_in[4];
  const float* bq1 = (const float*)d_in[5];
  const float* Wk0 = (const float*)d_in[6];
  const float* bk0 = (const float*)d_in[7];
  const float* Wk1 = (const float*)d_in[8];
  const float* bk1 = (const float*)d_in[9];
  const float* Wv0 = (const float*)d_in[10];
  const float* bv0 = (const float*)d_in[11];
  const float* Wv1 = (const float*)d_in[12];
  const float* bv1 = (const float*)d_in[13];
  const float* Wp0 = (const float*)d_in[14];
  const float* bp0 = (const float*)d_in[15];
  const float* Wp1 = (const float*)d_in[16];
  const float* bp1 = (const float*)d_in[17];
  float* out = (float*)d_out;

  char* p = (char*)d_ws;
  __bf16* qk_ws = (__bf16*)p; p += (size_t)8 * NPAD * 64 * 2;      // 102,760,448
  __bf16* Xb    = (__bf16*)p; p += (size_t)NPAD * 128 * 2;         //  25,690,112
  __bf16* W0t   = (__bf16*)p; p += (size_t)24 * 32768 * 2;         //   1,572,864
  __bf16* W1t   = (__bf16*)p; p += (size_t)24 * 16384 * 2;         //     786,432
  __bf16* Wp0t  = (__bf16*)p; p += (size_t)256 * 512 * 2;          //     262,144
  __bf16* Wp1t  = (__bf16*)p; p += (size_t)128 * 256 * 2;          //      65,536
  float*  parts = (float*)p;  p += (size_t)256 * 8 * 4160 * 4;     //  34,078,720
  float*  sumk  = (float*)p;  p += (size_t)512 * 4;                //       2,048
  __bf16* kvTe  = (__bf16*)p; p += (size_t)8 * 64 * 64 * 2;        //      65,536

  k_prep_x<<<2048, 256, 0, stream>>>(coords, Xb);
  k_prep_w<<<1024, 256, 0, stream>>>(Wq0, Wk0, Wv0, Wq1, Wk1, Wv1, Wp0, Wp1,
                                     W0t, W1t, Wp0t, Wp1t);
  k_mlp<<<256, 448, 0, stream>>>(Xb, mask, W0t, W1t, bq0, bq1, bk0, bk1, bv0, bv1,
                                 qk_ws, parts);
  k_kvt<<<130, 256, 0, stream>>>(parts, kvTe, sumk);
  k_cd<<<784, 512, 0, stream>>>(mask, qk_ws, kvTe, sumk, Wp0t, Wp1t, bp0, bp1, out);
}

// Round 5
// 849.461 us; speedup vs baseline: 3.1779x; 1.0132x over previous
//
#include <hip/hip_runtime.h>
#include <hip/hip_bf16.h>
#include <math.h>

// N=100000, D=128, H=8, HID=256, QK=64, V=64, PSI_HID=256, OUT=128
#define NPTS 100000
#define NPAD 100352           // 448 * 224 = 784 * 128
#define NGRP 448
#define KSTRIDE 232           // padded kkT/vT row stride (464B = 20 dwords mod 32)

typedef __bf16 bf16x8 __attribute__((ext_vector_type(8)));
typedef __bf16 bf16x4 __attribute__((ext_vector_type(4)));
typedef float f32x4 __attribute__((ext_vector_type(4)));

#define MFMA16(a,b,c) __builtin_amdgcn_mfma_f32_16x16x32_bf16((a),(b),(c),0,0,0)
#define SW(row) (((row)&7)<<3)

// ---------- prep: coordinates -> bf16, zero-padded to NPAD ----------
__global__ void k_prep_x(const float* __restrict__ coords, __bf16* __restrict__ Xb) {
  const int total = NPAD * 16;
  for (int c = blockIdx.x * 256 + threadIdx.x; c < total; c += gridDim.x * 256) {
    int row = c >> 4;
    int e8 = (c & 15) << 3;
    bf16x8 v = {};
    if (row < NPTS) {
      const float4* p = (const float4*)(coords + (size_t)row * 128 + e8);
      float4 f0 = p[0], f1 = p[1];
      v[0] = (__bf16)f0.x; v[1] = (__bf16)f0.y; v[2] = (__bf16)f0.z; v[3] = (__bf16)f0.w;
      v[4] = (__bf16)f1.x; v[5] = (__bf16)f1.y; v[6] = (__bf16)f1.z; v[7] = (__bf16)f1.w;
    }
    *(bf16x8*)(Xb + (size_t)row * 128 + e8) = v;
  }
}

// ---------- prep: weights cast/transpose ----------
__global__ void k_prep_w(const float* __restrict__ Wq0, const float* __restrict__ Wk0,
                         const float* __restrict__ Wv0, const float* __restrict__ Wq1,
                         const float* __restrict__ Wk1, const float* __restrict__ Wv1,
                         const float* __restrict__ Wp0, const float* __restrict__ Wp1,
                         __bf16* __restrict__ W0t, __bf16* __restrict__ W1t,
                         __bf16* __restrict__ Wp0t, __bf16* __restrict__ Wp1t) {
  for (int i = blockIdx.x * 256 + threadIdx.x; i < 1343488; i += gridDim.x * 256) {
    if (i < 786432) {                      // W0t [24][256 hid][128 d]
      int g = i >> 15, j = i & 32767;
      int mat = g >> 3, h = g & 7, mcol = j >> 7, k = j & 127;
      const float* src = (mat == 0) ? Wq0 : (mat == 1) ? Wk0 : Wv0;
      W0t[i] = (__bf16)src[h * 32768 + k * 256 + mcol];
    } else if (i < 1179648) {              // W1t [24][64 o][256 hid]
      int t = i - 786432;
      int g = t >> 14, j = t & 16383;
      int mat = g >> 3, h = g & 7, ocol = j >> 8, k = j & 255;
      const float* src = (mat == 0) ? Wq1 : (mat == 1) ? Wk1 : Wv1;
      W1t[t] = (__bf16)src[h * 16384 + k * 64 + ocol];
    } else if (i < 1310720) {              // Wp0t [256][512]
      int t = i - 1179648;
      int col = t >> 9, k = t & 511;
      Wp0t[t] = (__bf16)Wp0[k * 256 + col];
    } else {                               // Wp1t [128][256]
      int t = i - 1310720;
      int col = t >> 8, k = t & 255;
      Wp1t[t] = (__bf16)Wp1[k * 128 + col];
    }
  }
}

// ---------- two-layer MLP over one weight-half (128 hidden cols) ----------
// SWAP=true: layer2 output transposed (lane = x-row) for packed row-major stores.
template<bool SWAP>
__device__ __forceinline__ void compute_half(
    const __bf16* __restrict__ sW0, const __bf16* __restrict__ sW1,
    __bf16* __restrict__ myHid, const bf16x8 (&ax)[2][4],
    const float* __restrict__ b0h, int l15, int lg, f32x4* acc2)
{
  #pragma unroll
  for (int cg = 0; cg < 2; ++cg) {
    f32x4 a1[4][2] = {};
    #pragma unroll
    for (int ks = 0; ks < 4; ++ks) {
      bf16x8 wa[4];
      #pragma unroll
      for (int fi = 0; fi < 4; ++fi) {
        int hl = cg * 64 + fi * 16 + l15;
        wa[fi] = *(const bf16x8*)&sW0[(hl * 128 + ks * 32 + lg * 8) ^ SW(hl)];
      }
      #pragma unroll
      for (int fi = 0; fi < 4; ++fi)
        #pragma unroll
        for (int jt = 0; jt < 2; ++jt)
          a1[fi][jt] = MFMA16(wa[fi], ax[jt][ks], a1[fi][jt]);
    }
    // bias + relu -> hidden [2 jt][16 x][64 hid], packed bf16x4
    #pragma unroll
    for (int fi = 0; fi < 4; ++fi) {
      f32x4 b0 = *(const f32x4*)&b0h[cg * 64 + fi * 16 + lg * 4];
      #pragma unroll
      for (int jt = 0; jt < 2; ++jt) {
        bf16x4 hv;
        #pragma unroll
        for (int r = 0; r < 4; ++r) {
          float v = a1[fi][jt][r] + b0[r];
          hv[r] = (__bf16)(v > 0.f ? v : 0.f);
        }
        *(bf16x4*)&myHid[jt * 1024 + ((l15 * 64 + fi * 16 + lg * 4) ^ SW(l15))] = hv;
      }
    }
    // layer2 partial over this 64-hid chunk
    #pragma unroll
    for (int ks2 = 0; ks2 < 2; ++ks2) {
      bf16x8 hb[2], wf[4];
      #pragma unroll
      for (int jt = 0; jt < 2; ++jt)
        hb[jt] = *(const bf16x8*)&myHid[jt * 1024 + ((l15 * 64 + ks2 * 32 + lg * 8) ^ SW(l15))];
      #pragma unroll
      for (int f = 0; f < 4; ++f) {
        int o = f * 16 + l15;
        wf[f] = *(const bf16x8*)&sW1[(o * 128 + cg * 64 + ks2 * 32 + lg * 8) ^ SW(o)];
      }
      #pragma unroll
      for (int f = 0; f < 4; ++f)
        #pragma unroll
        for (int jt = 0; jt < 2; ++jt) {
          if (SWAP) acc2[f * 2 + jt] = MFMA16(wf[f], hb[jt], acc2[f * 2 + jt]);
          else      acc2[jt * 4 + f] = MFMA16(hb[jt], wf[f], acc2[jt * 4 + f]);
        }
    }
  }
}

// ---------- fused QKV MLPs + kv/sumk partials ----------
// 448 blocks x 448 thr (7 waves), one 224-row group per block.
// Double-buffered weight staging: issue loads early, compute, ds_write late, 1 barrier/phase.
__global__ __launch_bounds__(448) void k_mlp(
    const __bf16* __restrict__ Xb, const float* __restrict__ mask,
    const __bf16* __restrict__ W0t, const __bf16* __restrict__ W1t,
    const float* __restrict__ bq0, const float* __restrict__ bq1,
    const float* __restrict__ bk0, const float* __restrict__ bk1,
    const float* __restrict__ bv0, const float* __restrict__ bv1,
    __bf16* __restrict__ qk_ws, float* __restrict__ parts)
{
  __shared__ __bf16 sW0[2][16384];          // 64KB dbuf: [128 hid][128 d] swizzled
  __shared__ __bf16 sW1[2][8192];           // 32KB dbuf: [64 o][128 hid] swizzled
  __shared__ __bf16 sKT[64 * KSTRIDE];      // 29KB: kk^T [kq][n], pad stride
  __shared__ __bf16 sVH[64 * KSTRIDE];      // 29KB: union {per-wave hid [7][2048]} / {v^T [j][n]}

  const int tid = threadIdx.x, w = tid >> 6, lane = tid & 63;
  const int l15 = lane & 15, lg = lane >> 4;
  const int g = blockIdx.x;
  const int base = g * 224 + w * 32;
  __bf16* myHid = sVH + w * 2048;

  // X rows in registers (read once); masks
  bf16x8 ax[2][4];
  #pragma unroll
  for (int jt = 0; jt < 2; ++jt)
    #pragma unroll
    for (int ks = 0; ks < 4; ++ks)
      ax[jt][ks] = *(const bf16x8*)(Xb + (size_t)(base + jt * 16 + l15) * 128 + ks * 32 + lg * 8);
  float mq[2];
  f32x4 mv[2];
  #pragma unroll
  for (int jt = 0; jt < 2; ++jt) {
    int rq = base + jt * 16 + l15;
    mq[jt] = (rq < NPTS) ? mask[rq] : 0.f;
    int rv = base + jt * 16 + lg * 4;
    if (rv + 3 < NPTS) mv[jt] = *(const f32x4*)&mask[rv];
    else {
      #pragma unroll
      for (int r = 0; r < 4; ++r) mv[jt][r] = (rv + r < NPTS) ? mask[rv + r] : 0.f;
    }
  }

  // staging registers + load/write helpers
  bf16x8 s0[5], s1[3];
  auto LOAD = [&](int p) {
    int h = p / 6, m = (p % 6) >> 1, half = p & 1;
    const __bf16* w0 = W0t + (size_t)(m * 8 + h) * 32768 + (size_t)half * 16384;
    const __bf16* w1 = W1t + (size_t)(m * 8 + h) * 16384 + half * 128;
    #pragma unroll
    for (int i = 0; i < 5; ++i) {
      int u = tid + i * 448;
      if (u < 2048) s0[i] = *(const bf16x8*)(w0 + (size_t)(u >> 4) * 128 + ((u & 15) << 3));
    }
    #pragma unroll
    for (int i = 0; i < 3; ++i) {
      int u = tid + i * 448;
      if (u < 1024) s1[i] = *(const bf16x8*)(w1 + (size_t)(u >> 4) * 256 + ((u & 15) << 3));
    }
  };
  auto WRITE = [&](int buf) {
    #pragma unroll
    for (int i = 0; i < 5; ++i) {
      int u = tid + i * 448;
      if (u < 2048) {
        int r = u >> 4, k8 = (u & 15) << 3;
        *(bf16x8*)&sW0[buf][(r * 128 + k8) ^ SW(r)] = s0[i];
      }
    }
    #pragma unroll
    for (int i = 0; i < 3; ++i) {
      int u = tid + i * 448;
      if (u < 1024) {
        int o = u >> 4, k8 = (u & 15) << 3;
        *(bf16x8*)&sW1[buf][(o * 128 + k8) ^ SW(o)] = s1[i];
      }
    }
  };

  LOAD(0); WRITE(0); __syncthreads();

  f32x4 acc2[8];
  bf16x8 ones;
  #pragma unroll
  for (int e = 0; e < 8; ++e) ones[e] = (__bf16)1.0f;

  #pragma unroll 1
  for (int p = 0; p < 48; ++p) {
    const int h = p / 6, m = (p % 6) >> 1, half = p & 1, buf = p & 1;
    if (p + 1 < 48) LOAD(p + 1);            // issue next-phase loads (hide under compute)
    if (half == 0) {
      #pragma unroll
      for (int i = 0; i < 8; ++i) acc2[i] = f32x4{0.f, 0.f, 0.f, 0.f};
    }
    const float* b0 = (m == 0) ? bq0 : (m == 1) ? bk0 : bv0;
    if (m == 0) compute_half<true >(sW0[buf], sW1[buf], myHid, ax, b0 + h * 256 + half * 128, l15, lg, acc2);
    else        compute_half<false>(sW0[buf], sW1[buf], myHid, ax, b0 + h * 256 + half * 128, l15, lg, acc2);

    if (half == 1) {
      if (m == 0) {
        // phi(q) -> qk_ws, packed row-major (swapped layout: lane = x-row)
        #pragma unroll
        for (int ft = 0; ft < 4; ++ft) {
          f32x4 b1 = *(const f32x4*)&bq1[h * 64 + ft * 16 + lg * 4];
          #pragma unroll
          for (int jt = 0; jt < 2; ++jt) {
            bf16x4 qv;
            f32x4 a = acc2[ft * 2 + jt];
            #pragma unroll
            for (int r = 0; r < 4; ++r) {
              float v = (a[r] + b1[r]) * mq[jt];
              qv[r] = (__bf16)(v > 0.f ? v + 1.f : __expf(v));
            }
            *(bf16x4*)(qk_ws + ((size_t)h * NPAD + base + jt * 16 + l15) * 64 + ft * 16 + lg * 4) = qv;
          }
        }
      } else if (m == 1) {
        // phi(k), pad rows forced to 0 -> sKT [kq][n]
        #pragma unroll
        for (int f = 0; f < 4; ++f) {
          float b1 = bk1[h * 64 + f * 16 + l15];
          #pragma unroll
          for (int jt = 0; jt < 2; ++jt) {
            bf16x4 k4;
            f32x4 a = acc2[jt * 4 + f];
            #pragma unroll
            for (int r = 0; r < 4; ++r) {
              int row = base + jt * 16 + lg * 4 + r;
              float v = (a[r] + b1) * mv[jt][r];
              k4[r] = (__bf16)((row < NPTS) ? (v > 0.f ? v + 1.f : __expf(v)) : 0.f);
            }
            *(bf16x4*)&sKT[(f * 16 + l15) * KSTRIDE + w * 32 + jt * 16 + lg * 4] = k4;
          }
        }
      } else {
        __syncthreads();                    // all waves' hidden reads done
        // v -> sVH as v^T [j][n]  (overwrites hid union region)
        #pragma unroll
        for (int f = 0; f < 4; ++f) {
          float b1 = bv1[h * 64 + f * 16 + l15];
          #pragma unroll
          for (int jt = 0; jt < 2; ++jt) {
            bf16x4 v4;
            f32x4 a = acc2[jt * 4 + f];
            #pragma unroll
            for (int r = 0; r < 4; ++r)
              v4[r] = (__bf16)((a[r] + b1) * mv[jt][r]);
            *(bf16x4*)&sVH[(f * 16 + l15) * KSTRIDE + w * 32 + jt * 16 + lg * 4] = v4;
          }
        }
        __syncthreads();                    // vT (and kkT) complete
        // kv tiles (16) + sumk tiles (4): 20 tiles round-robin over 7 waves, K=224
        float* dst = parts + ((size_t)g * 8 + h) * 4160;
        for (int t = w; t < 20; t += 7) {
          f32x4 acc = {};
          if (t < 16) {
            int fi = t >> 2, fj = t & 3;
            #pragma unroll
            for (int ks = 0; ks < 7; ++ks) {
              bf16x8 a = *(const bf16x8*)&sKT[(fi * 16 + l15) * KSTRIDE + ks * 32 + lg * 8];
              bf16x8 b = *(const bf16x8*)&sVH[(fj * 16 + l15) * KSTRIDE + ks * 32 + lg * 8];
              acc = MFMA16(a, b, acc);
            }
            #pragma unroll
            for (int r = 0; r < 4; ++r)
              dst[(size_t)(fi * 16 + lg * 4 + r) * 64 + fj * 16 + l15] = acc[r];
          } else {
            int fi = t - 16;
            #pragma unroll
            for (int ks = 0; ks < 7; ++ks) {
              bf16x8 a = *(const bf16x8*)&sKT[(fi * 16 + l15) * KSTRIDE + ks * 32 + lg * 8];
              acc = MFMA16(a, ones, acc);
            }
            if (l15 == 0) {
              #pragma unroll
              for (int r = 0; r < 4; ++r)
                dst[4096 + fi * 16 + lg * 4 + r] = acc[r];
            }
          }
        }
      }
    }
    if (p + 1 < 48) WRITE((p + 1) & 1);     // ds_write late (vmcnt drains here)
    __syncthreads();
  }
}

// ---------- reduce parts -> kvTe bf16 [8][j][k], sumk f32 [512] ----------
__global__ void k_kvt(const float* __restrict__ parts, __bf16* __restrict__ kvTe,
                      float* __restrict__ sumk) {
  int i = blockIdx.x * 256 + threadIdx.x;
  if (i < 32768) {
    int h = i >> 12, rem = i & 4095;
    const float* src = parts + (size_t)h * 4160 + rem;
    float s = 0.f;
    for (int g = 0; g < NGRP; ++g) s += src[(size_t)g * 33280];
    int kq = rem >> 6, j = rem & 63;
    kvTe[((size_t)h * 64 + j) * 64 + kq] = (__bf16)s;
  } else if (i < 33280) {
    int t = i - 32768;
    const float* src = parts + (size_t)(t >> 6) * 4160 + 4096 + (t & 63);
    float s = 0.f;
    for (int g = 0; g < NGRP; ++g) s += src[(size_t)g * 33280];
    sumk[t] = s;
  }
}

// ---------- attention normalize + psi MLP ----------
__global__ __launch_bounds__(512, 2) void k_cd(
    const float* __restrict__ mask, const __bf16* __restrict__ qk_ws,
    const __bf16* __restrict__ kvTe, const float* __restrict__ sumk,
    const __bf16* __restrict__ Wp0t, const __bf16* __restrict__ Wp1t,
    const float* __restrict__ bp0, const float* __restrict__ bp1,
    float* __restrict__ out)
{
  __shared__ __bf16 sWp0c[16384];
  __shared__ __bf16 sCat[8192];
  __shared__ __bf16 sH2[32768];
  __shared__ float sSumk[512];

  const int tid = threadIdx.x, w = tid >> 6, lane = tid & 63, l15 = lane & 15, lg = lane >> 4;
  const int rbase = blockIdx.x * 128 + w * 16;
  __bf16* myCat = sCat + w * 1024;
  __bf16* myH2 = sH2 + w * 4096;

  sSumk[tid] = sumk[tid];

  f32x4 acc1[16] = {};
  for (int h = 0; h < 8; ++h) {
    __syncthreads();
    #pragma unroll
    for (int i = 0; i < 4; ++i) {
      int u = tid + i * 512;
      int col = u >> 3, koff = (u & 7) << 3;
      *(bf16x8*)&sWp0c[(col * 64 + koff) ^ SW(col)] =
          *(const bf16x8*)(Wp0t + (size_t)col * 512 + h * 64 + koff);
    }
    __syncthreads();
    bf16x8 axq[2];
    #pragma unroll
    for (int ks = 0; ks < 2; ++ks)
      axq[ks] = *(const bf16x8*)(qk_ws + ((size_t)h * NPAD + rbase + l15) * 64 + ks * 32 + lg * 8);
    f32x4 accn[4] = {};
    #pragma unroll
    for (int ks = 0; ks < 2; ++ks)
      #pragma unroll
      for (int f = 0; f < 4; ++f) {
        bf16x8 bv = *(const bf16x8*)(kvTe + ((size_t)h * 64 + f * 16 + l15) * 64 + ks * 32 + lg * 8);
        accn[f] = MFMA16(axq[ks], bv, accn[f]);
      }
    float p = 0.f;
    #pragma unroll
    for (int ks = 0; ks < 2; ++ks)
      #pragma unroll
      for (int e = 0; e < 8; ++e)
        p += (float)axq[ks][e] * sSumk[h * 64 + ks * 32 + lg * 8 + e];
    p += __shfl_xor(p, 16);
    p += __shfl_xor(p, 32);
    float dinv[4];
    #pragma unroll
    for (int r = 0; r < 4; ++r) {
      float d = __shfl(p, (lane & 48) + ((lane >> 4) << 2) + r);
      d = (d == 0.f) ? 1e-6f : d;
      dinv[r] = 1.f / d;
    }
    #pragma unroll
    for (int f = 0; f < 4; ++f)
      #pragma unroll
      for (int r = 0; r < 4; ++r) {
        int row = lg * 4 + r;
        myCat[(row * 64 + f * 16 + l15) ^ SW(row)] = (__bf16)(accn[f][r] * dinv[r]);
      }
    #pragma unroll
    for (int ks2 = 0; ks2 < 2; ++ks2) {
      bf16x8 aC = *(const bf16x8*)&myCat[(l15 * 64 + ks2 * 32 + lg * 8) ^ SW(l15)];
      #pragma unroll
      for (int f = 0; f < 16; ++f) {
        bf16x8 bw = *(const bf16x8*)&sWp0c[((f * 16 + l15) * 64 + ks2 * 32 + lg * 8) ^ SW(l15)];
        acc1[f] = MFMA16(aC, bw, acc1[f]);
      }
    }
  }
  #pragma unroll
  for (int f = 0; f < 16; ++f) {
    float bias = bp0[f * 16 + l15];
    #pragma unroll
    for (int r = 0; r < 4; ++r) {
      int row = lg * 4 + r;
      float val = acc1[f][r] + bias;
      val = val > 0.f ? val : 0.f;
      myH2[(row * 256 + f * 16 + l15) ^ SW(row)] = (__bf16)val;
    }
  }
  f32x4 acc2[8] = {};
  #pragma unroll
  for (int ks = 0; ks < 8; ++ks) {
    bf16x8 aH = *(const bf16x8*)&myH2[(l15 * 256 + ks * 32 + lg * 8) ^ SW(l15)];
    #pragma unroll
    for (int f = 0; f < 8; ++f) {
      bf16x8 bw = *(const bf16x8*)(Wp1t + (size_t)(f * 16 + l15) * 256 + ks * 32 + lg * 8);
      acc2[f] = MFMA16(aH, bw, acc2[f]);
    }
  }
  float mvr[4];
  #pragma unroll
  for (int r = 0; r < 4; ++r) {
    int grow = rbase + lg * 4 + r;
    mvr[r] = (grow < NPTS) ? mask[grow] : 0.f;
  }
  #pragma unroll
  for (int f = 0; f < 8; ++f) {
    int col = f * 16 + l15;
    float bias = bp1[col];
    #pragma unroll
    for (int r = 0; r < 4; ++r) {
      int grow = rbase + lg * 4 + r;
      if (grow < NPTS) out[(size_t)grow * 128 + col] = (acc2[f][r] + bias) * mvr[r];
    }
  }
}

extern "C" void kernel_launch(void* const* d_in, const int* in_sizes, int n_in,
                              void* d_out, int out_size, void* d_ws, size_t ws_size,
                              hipStream_t stream) {
  const float* coords = (const float*)d_in[0];
  const float* mask   = (const float*)d_in[1];
  const float* Wq0 = (const float*)d_in[2];
  const float* bq0 = (const float*)d_in[3];
  const float* Wq1 = (const float*)d_in[4];
  const float* bq1 = (const float*)d_in[5];
  const float* Wk0 = (const float*)d_in[6];
  const float* bk0 = (const float*)d_in[7];
  const float* Wk1 = (const float*)d_in[8];
  const float* bk1 = (const float*)d_in[9];
  const float* Wv0 = (const float*)d_in[10];
  const float* bv0 = (const float*)d_in[11];
  const float* Wv1 = (const float*)d_in[12];
  const float* bv1 = (const float*)d_in[13];
  const float* Wp0 = (const float*)d_in[14];
  const float* bp0 = (const float*)d_in[15];
  const float* Wp1 = (const float*)d_in[16];
  const float* bp1 = (const float*)d_in[17];
  float* out = (float*)d_out;

  char* p = (char*)d_ws;
  __bf16* qk_ws = (__bf16*)p; p += (size_t)8 * NPAD * 64 * 2;      // 102,760,448
  __bf16* Xb    = (__bf16*)p; p += (size_t)NPAD * 128 * 2;         //  25,690,112
  __bf16* W0t   = (__bf16*)p; p += (size_t)24 * 32768 * 2;         //   1,572,864
  __bf16* W1t   = (__bf16*)p; p += (size_t)24 * 16384 * 2;         //     786,432
  __bf16* Wp0t  = (__bf16*)p; p += (size_t)256 * 512 * 2;          //     262,144
  __bf16* Wp1t  = (__bf16*)p; p += (size_t)128 * 256 * 2;          //      65,536
  float*  parts = (float*)p;  p += (size_t)NGRP * 8 * 4160 * 4;    //  59,617,280
  float*  sumk  = (float*)p;  p += (size_t)512 * 4;                //       2,048
  __bf16* kvTe  = (__bf16*)p; p += (size_t)8 * 64 * 64 * 2;        //      65,536

  k_prep_x<<<2048, 256, 0, stream>>>(coords, Xb);
  k_prep_w<<<1024, 256, 0, stream>>>(Wq0, Wk0, Wv0, Wq1, Wk1, Wv1, Wp0, Wp1,
                                     W0t, W1t, Wp0t, Wp1t);
  k_mlp<<<NGRP, 448, 0, stream>>>(Xb, mask, W0t, W1t, bq0, bq1, bk0, bk1, bv0, bv1,
                                  qk_ws, parts);
  k_kvt<<<130, 256, 0, stream>>>(parts, kvTe, sumk);
  k_cd<<<784, 512, 0, stream>>>(mask, qk_ws, kvTe, sumk, Wp0t, Wp1t, bp0, bp1, out);
}